// Round 8
// baseline (254.141 us; speedup 1.0000x reference)
//
#include <hip/hip_runtime.h>

// CapsuleLayer: B=64, L=512, D=1024, C=32, O=64, 3 routing iters.
// u_hat never materialized:
//   dots[b,l,c] = in[b,l,:]@w_v[b,c,:] + bias_v[b,c]   (w_v[b,c,d] = sum_o fc_w[d,cO+o] v[b,c,o])
//   s_j[b,c,:]  = x_c[b,c,:]@fc_w[:,c,:] + csum[b,c]*fc_b[c,:]   (x_c = sum_l c_w * in)
// All contractions via mfma_f32_16x16x32_bf16 with direct global->fragment
// loads. Layouts: in_bf[b][l][d], in_T[b][d][l], fc_wT[co][d], fc_wb[d][co],
// c_wT[b][c][l], x_cb[c][b][d], v_bf[b][c][o], w_vb[b][c][d] (all bf16).
// k_ctr: LDS-free conv+transpose — each lane owns an 8l x 8d micro-tile,
// transposes in-register (u32 half-word packing); both store patterns
// coalesce to 8x128B segments per instruction. w_v fused into k_sv3 phase 2.

namespace {
constexpr int Bn = 64, Ln = 512, Dn = 1024, Cn = 32, On = 64, COn = Cn * On;
}

typedef float f32x4 __attribute__((ext_vector_type(4)));
typedef short bf16x8 __attribute__((ext_vector_type(8)));

static __device__ __forceinline__ unsigned f2bf(float f) {
    unsigned u = __float_as_uint(f);
    u += 0x7fff + ((u >> 16) & 1);   // RNE
    return u >> 16;
}

// ------------------------------------------------------------ conv+tr -------
// One pass over in fp32 [b][l][d], 64 l x 256 d per block (4 waves, each
// 64 l x 64 d; lane owns 8l x 8d). No LDS. Emits in_bf, in_T, rs_p.
__global__ __launch_bounds__(256) void k_ctr(const float* __restrict__ in,
                                             short* __restrict__ in_bf,
                                             short* __restrict__ in_T,
                                             float* __restrict__ rs_p) {
    int b = blockIdx.y;
    int lc = blockIdx.x >> 2, ds = blockIdx.x & 3;
    int l0 = lc * 64, d0 = ds * 256;
    int t = threadIdx.x, w = t >> 6, lane = t & 63;
    int db = lane & 7, lb = lane >> 3;
    int dloc = w * 64 + db * 8;       // d within 256-slab
    int lloc = lb * 8;                // l within 64-tile

    const float* src = in + ((size_t)b * Ln + l0 + lloc) * Dn + d0 + dloc;
    // 16 independent float4 loads (8 rows x 32B)
    float4 ld[8][2];
#pragma unroll
    for (int r = 0; r < 8; ++r) {
        ld[r][0] = *(const float4*)(src + (size_t)r * Dn);
        ld[r][1] = *(const float4*)(src + (size_t)r * Dn + 4);
    }
    // convert rows to packed u32 pairs + fp32 column sums
    unsigned mr[8][4];
    float s[8];
#pragma unroll
    for (int k = 0; k < 8; ++k) s[k] = 0.f;
#pragma unroll
    for (int r = 0; r < 8; ++r) {
        const float* e = (const float*)&ld[r][0];
#pragma unroll
        for (int j = 0; j < 4; ++j)
            mr[r][j] = f2bf(e[2 * j]) | (f2bf(e[2 * j + 1]) << 16);
#pragma unroll
        for (int k = 0; k < 8; ++k) s[k] += e[k];
    }
    // in_bf stores: row r, 16B per lane, 8x128B segments/instr
    short* dbf = in_bf + ((size_t)b * Ln + l0 + lloc) * Dn + d0 + dloc;
#pragma unroll
    for (int r = 0; r < 8; ++r)
        *(uint4*)(dbf + (size_t)r * Dn) = make_uint4(mr[r][0], mr[r][1], mr[r][2], mr[r][3]);
    // in_T stores: column k packed across rows (in-register transpose)
    short* dT = in_T + ((size_t)b * Dn + d0 + dloc) * Ln + l0 + lloc;
#pragma unroll
    for (int k = 0; k < 8; ++k) {
        int q = k >> 1;
        unsigned c0, c1, c2, c3;
        if (k & 1) {
            c0 = (mr[0][q] >> 16) | (mr[1][q] & 0xffff0000u);
            c1 = (mr[2][q] >> 16) | (mr[3][q] & 0xffff0000u);
            c2 = (mr[4][q] >> 16) | (mr[5][q] & 0xffff0000u);
            c3 = (mr[6][q] >> 16) | (mr[7][q] & 0xffff0000u);
        } else {
            c0 = (mr[0][q] & 0xffffu) | (mr[1][q] << 16);
            c1 = (mr[2][q] & 0xffffu) | (mr[3][q] << 16);
            c2 = (mr[4][q] & 0xffffu) | (mr[5][q] << 16);
            c3 = (mr[6][q] & 0xffffu) | (mr[7][q] << 16);
        }
        *(uint4*)(dT + (size_t)k * Ln) = make_uint4(c0, c1, c2, c3);
    }
    // rowsum partials: reduce over lb (lane bits 3..5)
#pragma unroll
    for (int k = 0; k < 8; ++k) {
        s[k] += __shfl_xor(s[k], 8, 64);
        s[k] += __shfl_xor(s[k], 16, 64);
        s[k] += __shfl_xor(s[k], 32, 64);
    }
    if (lb == 0) {
        float* rp = rs_p + ((size_t)b * 8 + lc) * Dn + d0 + dloc;
        *(float4*)rp = make_float4(s[0], s[1], s[2], s[3]);
        *(float4*)(rp + 4) = make_float4(s[4], s[5], s[6], s[7]);
    }
}

// ---------------------------------------------------------------- wprep -----
// fc_w fp32 [d][co] -> fc_wT bf16 [co][d]  +  fc_wb bf16 [d][co]
__global__ __launch_bounds__(256) void k_wprep(const float* __restrict__ fc_w,
                                               short* __restrict__ fc_wT,
                                               short* __restrict__ fc_wb) {
    __shared__ short tr[64 * 260];      // [d-row][co-col]
    int d0 = blockIdx.x * 64;           // 16
    int co0 = blockIdx.y * 256;         // 8
    int t = threadIdx.x, grp = t >> 6, cq = t & 63;
#pragma unroll
    for (int i = 0; i < 16; ++i) {
        int row = grp + 4 * i;
        float4 x = *(const float4*)(fc_w + (size_t)(d0 + row) * COn + co0 + cq * 4);
        short4 s4 = make_short4((short)f2bf(x.x), (short)f2bf(x.y),
                                (short)f2bf(x.z), (short)f2bf(x.w));
        *(short4*)(&tr[row * 260 + cq * 4]) = s4;
        *(short4*)(fc_wb + (size_t)(d0 + row) * COn + co0 + cq * 4) = s4;
    }
    __syncthreads();
#pragma unroll
    for (int i = 0; i < 8; ++i) {
        int idx = t + 256 * i;
        int corow = idx >> 3, slot = idx & 7;
        bf16x8 v;
#pragma unroll
        for (int j = 0; j < 8; ++j) v[j] = tr[(slot * 8 + j) * 260 + corow];
        *(bf16x8*)(fc_wT + (size_t)(co0 + corow) * Dn + d0 + slot * 8) = v;
    }
}

// ---------------------------------------------------------------- rsred -----
__global__ __launch_bounds__(256) void k_rsred(const float* __restrict__ rs_p,
                                               unsigned short* __restrict__ rs_bf) {
    int b = blockIdx.y, d = blockIdx.x * 256 + threadIdx.x;
    float s = 0.f;
#pragma unroll
    for (int lc = 0; lc < 8; ++lc) s += rs_p[((size_t)b * 8 + lc) * Dn + d];
    rs_bf[b * Dn + d] = (unsigned short)f2bf(s * (1.0f / 32.0f));
}

// ------------------------------------------------- s -> squash -> v (+w_v) --
// Per-c MFMA GEMM: S[64 b][64 o] = X(64x1024)@W_c(1024x64). Writes v_bf
// (bf16 [b][c][o]), f32 out when fout != nullptr (final iter), and when
// do_wv: phase 2 computes w_vb[b][c][d] = fc_wb[d][c,:] . v[b][c,:] via MFMA
// (reads back this block's own v_bf after __syncthreads; same-CU L2).
__global__ __launch_bounds__(256) void k_sv3(const short* __restrict__ xA,
                                             const float* __restrict__ csum_p,
                                             const short* __restrict__ fc_wT,
                                             const short* __restrict__ fc_wb,
                                             const float* __restrict__ fc_b,
                                             short* __restrict__ v_bf,
                                             short* __restrict__ w_vb,
                                             float* __restrict__ fout,
                                             float* __restrict__ bias_v,
                                             int mode0, int do_wv) {
    int c = blockIdx.x;
    int t = threadIdx.x, w = t >> 6, lane = t & 63;
    int l15 = lane & 15, lg = lane >> 4;
    const short* A = mode0 ? xA : (xA + (size_t)c * Bn * Dn);   // [b][d]
    const short* Bw = fc_wT + (size_t)c * On * Dn;              // [o][d]
    f32x4 acc[4];
#pragma unroll
    for (int i = 0; i < 4; ++i) acc[i] = {0.f, 0.f, 0.f, 0.f};
    for (int ks = 0; ks < 32; ++ks) {
        int koff = ks * 32 + lg * 8;
        bf16x8 a = *(const bf16x8*)(A + (size_t)(w * 16 + l15) * Dn + koff);
#pragma unroll
        for (int dt = 0; dt < 4; ++dt) {
            bf16x8 bbf = *(const bf16x8*)(Bw + (size_t)(dt * 16 + l15) * Dn + koff);
            acc[dt] = __builtin_amdgcn_mfma_f32_16x16x32_bf16(a, bbf, acc[dt], 0, 0, 0);
        }
    }
    float fb[4];
#pragma unroll
    for (int dt = 0; dt < 4; ++dt) fb[dt] = fc_b[c * On + dt * 16 + l15];
#pragma unroll
    for (int r = 0; r < 4; ++r) {
        int brow = w * 16 + lg * 4 + r;
        float cs;
        if (mode0) {
            cs = 16.0f;
        } else {
            cs = 0.f;
#pragma unroll
            for (int lt = 0; lt < 8; ++lt) cs += csum_p[((size_t)lt * Bn + brow) * Cn + c];
        }
        float s0 = acc[0][r] + cs * fb[0];
        float s1 = acc[1][r] + cs * fb[1];
        float s2 = acc[2][r] + cs * fb[2];
        float s3 = acc[3][r] + cs * fb[3];
        float sq = s0 * s0 + s1 * s1 + s2 * s2 + s3 * s3;
        sq += __shfl_xor(sq, 1, 64); sq += __shfl_xor(sq, 2, 64);
        sq += __shfl_xor(sq, 4, 64); sq += __shfl_xor(sq, 8, 64);
        float scale = sq / (1.0f + sq) * rsqrtf(sq + 1e-8f);
        float v0 = scale * s0, v1 = scale * s1, v2 = scale * s2, v3 = scale * s3;
        size_t vo = ((size_t)brow * Cn + c) * On;
        v_bf[vo + 0 * 16 + l15] = (short)f2bf(v0);
        v_bf[vo + 1 * 16 + l15] = (short)f2bf(v1);
        v_bf[vo + 2 * 16 + l15] = (short)f2bf(v2);
        v_bf[vo + 3 * 16 + l15] = (short)f2bf(v3);
        if (fout) {
            fout[vo + 0 * 16 + l15] = v0;
            fout[vo + 1 * 16 + l15] = v1;
            fout[vo + 2 * 16 + l15] = v2;
            fout[vo + 3 * 16 + l15] = v3;
        }
        float bv = fb[0] * v0 + fb[1] * v1 + fb[2] * v2 + fb[3] * v3;
        bv += __shfl_xor(bv, 1, 64); bv += __shfl_xor(bv, 2, 64);
        bv += __shfl_xor(bv, 4, 64); bv += __shfl_xor(bv, 8, 64);
        if (l15 == 0) bias_v[brow * Cn + c] = bv;
    }

    if (do_wv) {
        __syncthreads();   // drains vmcnt -> this block's v_bf visible via L2
        // wave w: d-slab [w*256, +256): 16 m-tiles x (4 b n-tiles), K=o=64
#pragma unroll 4
        for (int mt = 0; mt < 16; ++mt) {
            int dd = w * 256 + mt * 16;
            f32x4 acc2[4];
#pragma unroll
            for (int nt = 0; nt < 4; ++nt) acc2[nt] = {0.f, 0.f, 0.f, 0.f};
#pragma unroll
            for (int ks = 0; ks < 2; ++ks) {
                int o = ks * 32 + lg * 8;
                bf16x8 a2 = *(const bf16x8*)(fc_wb + (size_t)(dd + l15) * COn + c * On + o);
#pragma unroll
                for (int nt = 0; nt < 4; ++nt) {
                    bf16x8 b2 = *(const bf16x8*)(v_bf + ((size_t)(nt * 16 + l15) * Cn + c) * On + o);
                    acc2[nt] = __builtin_amdgcn_mfma_f32_16x16x32_bf16(a2, b2, acc2[nt], 0, 0, 0);
                }
            }
#pragma unroll
            for (int nt = 0; nt < 4; ++nt) {
                int bb = nt * 16 + l15;
                *(short4*)(w_vb + ((size_t)bb * Cn + c) * Dn + dd + lg * 4) =
                    make_short4((short)f2bf(acc2[nt][0]), (short)f2bf(acc2[nt][1]),
                                (short)f2bf(acc2[nt][2]), (short)f2bf(acc2[nt][3]));
            }
        }
    }
}

// ------------------------------- dots -> b_ij update -> softmax -> c_wT -----
// grid (8 lt, 64 b), 256 thr / 4 waves, wave = 16 l-rows x 32 c. MFMA,
// A-frags straight from in_bf (bf16), B = w_v bf16 rows.
__global__ __launch_bounds__(256) void k_route_m(const short* __restrict__ in_bf,
                                                 const short* __restrict__ w_v,
                                                 const float* __restrict__ bias_v,
                                                 float* __restrict__ b_ij,
                                                 short* __restrict__ c_wT,
                                                 float* __restrict__ csum_p,
                                                 int first) {
    __shared__ short cw_sh[Cn * 68];
    __shared__ float cs_sh[4][Cn];
    int lt = blockIdx.x, b = blockIdx.y;
    int t = threadIdx.x, w = t >> 6, lane = t & 63;
    int l15 = lane & 15, lg = lane >> 4;
    int l0 = lt * 64;
    f32x4 acc0 = {0.f, 0.f, 0.f, 0.f}, acc1 = {0.f, 0.f, 0.f, 0.f};
    const short* Ap = in_bf + ((size_t)b * Ln + l0 + w * 16 + l15) * Dn;
    const short* Bp = w_v + (size_t)b * Cn * Dn;
    for (int ks = 0; ks < 32; ++ks) {
        int koff = ks * 32 + lg * 8;
        bf16x8 a = *(const bf16x8*)(Ap + koff);
        bf16x8 b0 = *(const bf16x8*)(Bp + (size_t)l15 * Dn + koff);
        bf16x8 b1 = *(const bf16x8*)(Bp + (size_t)(l15 + 16) * Dn + koff);
        acc0 = __builtin_amdgcn_mfma_f32_16x16x32_bf16(a, b0, acc0, 0, 0, 0);
        acc1 = __builtin_amdgcn_mfma_f32_16x16x32_bf16(a, b1, acc1, 0, 0, 0);
    }
    float bv0 = bias_v[b * Cn + l15];
    float bv1 = bias_v[b * Cn + l15 + 16];
    float csa0 = 0.f, csa1 = 0.f;
#pragma unroll
    for (int r = 0; r < 4; ++r) {
        int lrow = l0 + w * 16 + lg * 4 + r;
        size_t boff = ((size_t)b * Ln + lrow) * Cn;
        float d0 = acc0[r] + bv0, d1 = acc1[r] + bv1;
        if (!first) { d0 += b_ij[boff + l15]; d1 += b_ij[boff + l15 + 16]; }
        b_ij[boff + l15] = d0;
        b_ij[boff + l15 + 16] = d1;
        float m = fmaxf(d0, d1);
        m = fmaxf(m, __shfl_xor(m, 1, 64)); m = fmaxf(m, __shfl_xor(m, 2, 64));
        m = fmaxf(m, __shfl_xor(m, 4, 64)); m = fmaxf(m, __shfl_xor(m, 8, 64));
        float e0 = __expf(d0 - m), e1 = __expf(d1 - m);
        float sm = e0 + e1;
        sm += __shfl_xor(sm, 1, 64); sm += __shfl_xor(sm, 2, 64);
        sm += __shfl_xor(sm, 4, 64); sm += __shfl_xor(sm, 8, 64);
        float inv = 1.0f / sm;
        float cw0 = e0 * inv, cw1 = e1 * inv;
        csa0 += cw0; csa1 += cw1;
        int ll = w * 16 + lg * 4 + r;
        cw_sh[l15 * 68 + ll] = (short)f2bf(cw0);
        cw_sh[(l15 + 16) * 68 + ll] = (short)f2bf(cw1);
    }
    csa0 += __shfl_xor(csa0, 16, 64); csa0 += __shfl_xor(csa0, 32, 64);
    csa1 += __shfl_xor(csa1, 16, 64); csa1 += __shfl_xor(csa1, 32, 64);
    if (lg == 0) { cs_sh[w][l15] = csa0; cs_sh[w][l15 + 16] = csa1; }
    __syncthreads();
    if (t < Cn) {
        float s = cs_sh[0][t] + cs_sh[1][t] + cs_sh[2][t] + cs_sh[3][t];
        csum_p[((size_t)lt * Bn + b) * Cn + t] = s;
    }
    {
        int cc = t >> 3, slot = t & 7;
        bf16x8 vv;
#pragma unroll
        for (int j = 0; j < 8; ++j) vv[j] = cw_sh[cc * 68 + slot * 8 + j];
        *(bf16x8*)(c_wT + ((size_t)b * Cn + cc) * Ln + l0 + slot * 8) = vv;
    }
}

// ----------------------------------------- x_cb[c][b][d] = c_w^T @ in -------
// grid (8 dt, 64 b), 256 thr / 4 waves; wave covers 32 d (2 x 16).
__global__ __launch_bounds__(256) void k_xc_m(const short* __restrict__ in_T,
                                              const short* __restrict__ c_wT,
                                              short* __restrict__ x_cb) {
    int dt = blockIdx.x, b = blockIdx.y;
    int t = threadIdx.x, w = t >> 6, lane = t & 63;
    int l15 = lane & 15, lg = lane >> 4;
    f32x4 acc[2][2];
#pragma unroll
    for (int h = 0; h < 2; ++h)
#pragma unroll
        for (int dd = 0; dd < 2; ++dd) acc[h][dd] = {0.f, 0.f, 0.f, 0.f};
    const short* A = c_wT + (size_t)b * Cn * Ln;                        // [c][l]
    const short* Bp = in_T + ((size_t)b * Dn + dt * 128 + w * 32) * Ln; // [d][l]
    for (int ks = 0; ks < 16; ++ks) {
        int koff = ks * 32 + lg * 8;
        bf16x8 a0 = *(const bf16x8*)(A + (size_t)l15 * Ln + koff);
        bf16x8 a1 = *(const bf16x8*)(A + (size_t)(l15 + 16) * Ln + koff);
#pragma unroll
        for (int dd = 0; dd < 2; ++dd) {
            bf16x8 bb = *(const bf16x8*)(Bp + (size_t)(dd * 16 + l15) * Ln + koff);
            acc[0][dd] = __builtin_amdgcn_mfma_f32_16x16x32_bf16(a0, bb, acc[0][dd], 0, 0, 0);
            acc[1][dd] = __builtin_amdgcn_mfma_f32_16x16x32_bf16(a1, bb, acc[1][dd], 0, 0, 0);
        }
    }
#pragma unroll
    for (int h = 0; h < 2; ++h)
#pragma unroll
        for (int dd = 0; dd < 2; ++dd)
#pragma unroll
            for (int r = 0; r < 4; ++r) {
                int c = 16 * h + lg * 4 + r;
                int d = dt * 128 + w * 32 + dd * 16 + l15;
                x_cb[((size_t)c * Bn + b) * Dn + d] = (short)f2bf(acc[h][dd][r]);
            }
}

// ---------------------------------------------------------------------------
extern "C" void kernel_launch(void* const* d_in, const int* in_sizes, int n_in,
                              void* d_out, int out_size, void* d_ws, size_t ws_size,
                              hipStream_t stream) {
    const float* in   = (const float*)d_in[0];
    const float* fc_w = (const float*)d_in[1];
    const float* fc_b = (const float*)d_in[2];
    float* out = (float*)d_out;

    char* p = (char*)d_ws;
    auto alloc = [&](size_t bytes) -> char* {
        char* r = p;
        p += (bytes + 255) & ~(size_t)255;
        return r;
    };
    short* in_bf  = (short*)alloc((size_t)Bn * Ln * Dn * 2);   // 64 MB
    short* in_T   = (short*)alloc((size_t)Bn * Dn * Ln * 2);   // 64 MB
    short* fc_wT  = (short*)alloc((size_t)COn * Dn * 2);       // 4 MB
    short* fc_wb  = (short*)alloc((size_t)COn * Dn * 2);       // 4 MB
    short* w_vb   = (short*)alloc((size_t)Bn * Cn * Dn * 2);   // 4 MB
    short* c_wT   = (short*)alloc((size_t)Bn * Cn * Ln * 2);   // 2 MB
    short* x_cb   = (short*)alloc((size_t)Cn * Bn * Dn * 2);   // 4 MB
    short* v_bf   = (short*)alloc((size_t)Bn * Cn * On * 2);   // 256 KB
    float* rs_p   = (float*)alloc((size_t)Bn * 8 * Dn * 4);    // 2 MB
    unsigned short* rs_bf = (unsigned short*)alloc((size_t)Bn * Dn * 2);
    float* b_ij   = (float*)alloc((size_t)Bn * Ln * Cn * 4);   // 4 MB
    float* bias_v = (float*)alloc((size_t)Bn * Cn * 4);
    float* csum_p = (float*)alloc((size_t)8 * Bn * Cn * 4);

    k_ctr<<<dim3(32, Bn), 256, 0, stream>>>(in, in_bf, in_T, rs_p);
    k_wprep<<<dim3(16, 8), 256, 0, stream>>>(fc_w, fc_wT, fc_wb);
    k_rsred<<<dim3(4, Bn), 256, 0, stream>>>(rs_p, rs_bf);
    k_sv3<<<Cn, 256, 0, stream>>>((const short*)rs_bf, csum_p, fc_wT, fc_wb,
                                  fc_b, v_bf, w_vb, nullptr, bias_v, 1, 1);
    for (int it = 1; it <= 2; ++it) {
        k_route_m<<<dim3(8, Bn), 256, 0, stream>>>(in_bf, w_vb, bias_v, b_ij,
                                                   c_wT, csum_p, (it == 1) ? 1 : 0);
        k_xc_m<<<dim3(8, Bn), 256, 0, stream>>>(in_T, c_wT, x_cb);
        k_sv3<<<Cn, 256, 0, stream>>>(x_cb, csum_p, fc_wT, fc_wb, fc_b,
                                      v_bf, w_vb, (it == 2) ? out : nullptr,
                                      bias_v, 0, (it == 1) ? 1 : 0);
    }
}

// Round 9
// 225.608 us; speedup vs baseline: 1.1265x; 1.1265x over previous
//
#include <hip/hip_runtime.h>

// CapsuleLayer: B=64, L=512, D=1024, C=32, O=64, 3 routing iters.
// u_hat never materialized:
//   dots[b,l,c] = in[b,l,:]@w_v[b,c,:] + bias_v[b,c]   (w_v[b,c,d] = sum_o fc_w[d,cO+o] v[b,c,o])
//   s_j[b,c,:]  = x_c[b,c,:]@fc_w[:,c,:] + csum[b,c]*fc_b[c,:]   (x_c = sum_l c_w * in)
// All contractions via mfma_f32_16x16x32_bf16. Single bf16 input copy
// in_bf[b][l][d] (no in_T): k_xc_m builds l-contiguous B-fragments by
// staging in_bf tiles through LDS (u32 l-pair pack, XOR-chunk swizzle;
// writes 2-way/free, ds_read_b128 2-way/free). k_ctr writes 66 MB not 130.

namespace {
constexpr int Bn = 64, Ln = 512, Dn = 1024, Cn = 32, On = 64, COn = Cn * On;
}

typedef float f32x4 __attribute__((ext_vector_type(4)));
typedef short bf16x8 __attribute__((ext_vector_type(8)));

static __device__ __forceinline__ unsigned f2bf(float f) {
    unsigned u = __float_as_uint(f);
    u += 0x7fff + ((u >> 16) & 1);   // RNE
    return u >> 16;
}

// ------------------------------------------------------------ conv ----------
// One pass over in fp32 [b][l][d], 64 l x 256 d per block; lane owns
// 8l x 8d micro-tile. No LDS. Emits in_bf + rowsum partials only.
__global__ __launch_bounds__(256) void k_ctr(const float* __restrict__ in,
                                             short* __restrict__ in_bf,
                                             float* __restrict__ rs_p) {
    int b = blockIdx.y;
    int lc = blockIdx.x >> 2, ds = blockIdx.x & 3;
    int l0 = lc * 64, d0 = ds * 256;
    int t = threadIdx.x, w = t >> 6, lane = t & 63;
    int db = lane & 7, lb = lane >> 3;
    int dloc = w * 64 + db * 8;
    int lloc = lb * 8;

    const float* src = in + ((size_t)b * Ln + l0 + lloc) * Dn + d0 + dloc;
    float4 ld[8][2];
#pragma unroll
    for (int r = 0; r < 8; ++r) {
        ld[r][0] = *(const float4*)(src + (size_t)r * Dn);
        ld[r][1] = *(const float4*)(src + (size_t)r * Dn + 4);
    }
    unsigned mr[8][4];
    float s[8];
#pragma unroll
    for (int k = 0; k < 8; ++k) s[k] = 0.f;
#pragma unroll
    for (int r = 0; r < 8; ++r) {
        const float* e = (const float*)&ld[r][0];
#pragma unroll
        for (int j = 0; j < 4; ++j)
            mr[r][j] = f2bf(e[2 * j]) | (f2bf(e[2 * j + 1]) << 16);
#pragma unroll
        for (int k = 0; k < 8; ++k) s[k] += e[k];
    }
    short* dbf = in_bf + ((size_t)b * Ln + l0 + lloc) * Dn + d0 + dloc;
#pragma unroll
    for (int r = 0; r < 8; ++r)
        *(uint4*)(dbf + (size_t)r * Dn) = make_uint4(mr[r][0], mr[r][1], mr[r][2], mr[r][3]);
#pragma unroll
    for (int k = 0; k < 8; ++k) {
        s[k] += __shfl_xor(s[k], 8, 64);
        s[k] += __shfl_xor(s[k], 16, 64);
        s[k] += __shfl_xor(s[k], 32, 64);
    }
    if (lb == 0) {
        float* rp = rs_p + ((size_t)b * 8 + lc) * Dn + d0 + dloc;
        *(float4*)rp = make_float4(s[0], s[1], s[2], s[3]);
        *(float4*)(rp + 4) = make_float4(s[4], s[5], s[6], s[7]);
    }
}

// ---------------------------------------------------------------- wprep -----
// fc_w fp32 [d][co] -> fc_wT bf16 [co][d]  +  fc_wb bf16 [d][co]
__global__ __launch_bounds__(256) void k_wprep(const float* __restrict__ fc_w,
                                               short* __restrict__ fc_wT,
                                               short* __restrict__ fc_wb) {
    __shared__ short tr[64 * 260];      // [d-row][co-col]
    int d0 = blockIdx.x * 64;           // 16
    int co0 = blockIdx.y * 256;         // 8
    int t = threadIdx.x, grp = t >> 6, cq = t & 63;
#pragma unroll
    for (int i = 0; i < 16; ++i) {
        int row = grp + 4 * i;
        float4 x = *(const float4*)(fc_w + (size_t)(d0 + row) * COn + co0 + cq * 4);
        short4 s4 = make_short4((short)f2bf(x.x), (short)f2bf(x.y),
                                (short)f2bf(x.z), (short)f2bf(x.w));
        *(short4*)(&tr[row * 260 + cq * 4]) = s4;
        *(short4*)(fc_wb + (size_t)(d0 + row) * COn + co0 + cq * 4) = s4;
    }
    __syncthreads();
#pragma unroll
    for (int i = 0; i < 8; ++i) {
        int idx = t + 256 * i;
        int corow = idx >> 3, slot = idx & 7;
        bf16x8 v;
#pragma unroll
        for (int j = 0; j < 8; ++j) v[j] = tr[(slot * 8 + j) * 260 + corow];
        *(bf16x8*)(fc_wT + (size_t)(co0 + corow) * Dn + d0 + slot * 8) = v;
    }
}

// ---------------------------------------------------------------- rsred -----
__global__ __launch_bounds__(256) void k_rsred(const float* __restrict__ rs_p,
                                               unsigned short* __restrict__ rs_bf) {
    int b = blockIdx.y, d = blockIdx.x * 256 + threadIdx.x;
    float s = 0.f;
#pragma unroll
    for (int lc = 0; lc < 8; ++lc) s += rs_p[((size_t)b * 8 + lc) * Dn + d];
    rs_bf[b * Dn + d] = (unsigned short)f2bf(s * (1.0f / 32.0f));
}

// ------------------------------------------------------- s -> squash -> v ---
// Per-c MFMA GEMM: S[64 b][64 o] = X(64x1024)@W_c(1024x64).
__global__ __launch_bounds__(256) void k_sv3(const short* __restrict__ xA,
                                             const float* __restrict__ csum_p,
                                             const short* __restrict__ fc_wT,
                                             const float* __restrict__ fc_b,
                                             short* __restrict__ v_bf,
                                             float* __restrict__ fout,
                                             float* __restrict__ bias_v,
                                             int mode0) {
    int c = blockIdx.x;
    int t = threadIdx.x, w = t >> 6, lane = t & 63;
    int l15 = lane & 15, lg = lane >> 4;
    const short* A = mode0 ? xA : (xA + (size_t)c * Bn * Dn);   // [b][d]
    const short* Bw = fc_wT + (size_t)c * On * Dn;              // [o][d]
    f32x4 acc[4];
#pragma unroll
    for (int i = 0; i < 4; ++i) acc[i] = {0.f, 0.f, 0.f, 0.f};
    for (int ks = 0; ks < 32; ++ks) {
        int koff = ks * 32 + lg * 8;
        bf16x8 a = *(const bf16x8*)(A + (size_t)(w * 16 + l15) * Dn + koff);
#pragma unroll
        for (int dt = 0; dt < 4; ++dt) {
            bf16x8 bbf = *(const bf16x8*)(Bw + (size_t)(dt * 16 + l15) * Dn + koff);
            acc[dt] = __builtin_amdgcn_mfma_f32_16x16x32_bf16(a, bbf, acc[dt], 0, 0, 0);
        }
    }
    float fb[4];
#pragma unroll
    for (int dt = 0; dt < 4; ++dt) fb[dt] = fc_b[c * On + dt * 16 + l15];
#pragma unroll
    for (int r = 0; r < 4; ++r) {
        int brow = w * 16 + lg * 4 + r;
        float cs;
        if (mode0) {
            cs = 16.0f;
        } else {
            cs = 0.f;
#pragma unroll
            for (int lt = 0; lt < 8; ++lt) cs += csum_p[((size_t)lt * Bn + brow) * Cn + c];
        }
        float s0 = acc[0][r] + cs * fb[0];
        float s1 = acc[1][r] + cs * fb[1];
        float s2 = acc[2][r] + cs * fb[2];
        float s3 = acc[3][r] + cs * fb[3];
        float sq = s0 * s0 + s1 * s1 + s2 * s2 + s3 * s3;
        sq += __shfl_xor(sq, 1, 64); sq += __shfl_xor(sq, 2, 64);
        sq += __shfl_xor(sq, 4, 64); sq += __shfl_xor(sq, 8, 64);
        float scale = sq / (1.0f + sq) * rsqrtf(sq + 1e-8f);
        float v0 = scale * s0, v1 = scale * s1, v2 = scale * s2, v3 = scale * s3;
        size_t vo = ((size_t)brow * Cn + c) * On;
        v_bf[vo + 0 * 16 + l15] = (short)f2bf(v0);
        v_bf[vo + 1 * 16 + l15] = (short)f2bf(v1);
        v_bf[vo + 2 * 16 + l15] = (short)f2bf(v2);
        v_bf[vo + 3 * 16 + l15] = (short)f2bf(v3);
        if (fout) {
            fout[vo + 0 * 16 + l15] = v0;
            fout[vo + 1 * 16 + l15] = v1;
            fout[vo + 2 * 16 + l15] = v2;
            fout[vo + 3 * 16 + l15] = v3;
        }
        float bv = fb[0] * v0 + fb[1] * v1 + fb[2] * v2 + fb[3] * v3;
        bv += __shfl_xor(bv, 1, 64); bv += __shfl_xor(bv, 2, 64);
        bv += __shfl_xor(bv, 4, 64); bv += __shfl_xor(bv, 8, 64);
        if (l15 == 0) bias_v[brow * Cn + c] = bv;
    }
}

// ------------------------------------------- w_v via MFMA (contract o=64) ---
// grid (4 dslab, 32 c), 256 thr / 4 waves; wave: 64 d x 64 b, K=64.
__global__ __launch_bounds__(256) void k_wv_m(const short* __restrict__ fc_wb,
                                              const short* __restrict__ v_bf,
                                              short* __restrict__ w_vb) {
    int dsl = blockIdx.x, c = blockIdx.y;
    int t = threadIdx.x, w = t >> 6, lane = t & 63;
    int l15 = lane & 15, lg = lane >> 4;
    int dbase = dsl * 256 + w * 64;
    f32x4 acc[4][4];
#pragma unroll
    for (int i = 0; i < 4; ++i)
#pragma unroll
        for (int j = 0; j < 4; ++j) acc[i][j] = {0.f, 0.f, 0.f, 0.f};
#pragma unroll
    for (int ks = 0; ks < 2; ++ks) {
        int o = ks * 32 + lg * 8;
        bf16x8 bfr[4];
#pragma unroll
        for (int nt = 0; nt < 4; ++nt)
            bfr[nt] = *(const bf16x8*)(v_bf + ((size_t)(nt * 16 + l15) * Cn + c) * On + o);
#pragma unroll
        for (int mt = 0; mt < 4; ++mt) {
            bf16x8 a = *(const bf16x8*)(fc_wb + (size_t)(dbase + mt * 16 + l15) * COn + c * On + o);
#pragma unroll
            for (int nt = 0; nt < 4; ++nt)
                acc[mt][nt] = __builtin_amdgcn_mfma_f32_16x16x32_bf16(a, bfr[nt], acc[mt][nt], 0, 0, 0);
        }
    }
#pragma unroll
    for (int mt = 0; mt < 4; ++mt)
#pragma unroll
        for (int nt = 0; nt < 4; ++nt) {
            int bb = nt * 16 + l15;
            int d = dbase + mt * 16 + lg * 4;
            *(short4*)(w_vb + ((size_t)bb * Cn + c) * Dn + d) =
                make_short4((short)f2bf(acc[mt][nt][0]), (short)f2bf(acc[mt][nt][1]),
                            (short)f2bf(acc[mt][nt][2]), (short)f2bf(acc[mt][nt][3]));
        }
}

// ------------------------------- dots -> b_ij update -> softmax -> c_wT -----
// grid (8 lt, 64 b), 256 thr / 4 waves, wave = 16 l-rows x 32 c. MFMA,
// A-frags straight from in_bf (bf16), B = w_v bf16 rows.
__global__ __launch_bounds__(256) void k_route_m(const short* __restrict__ in_bf,
                                                 const short* __restrict__ w_v,
                                                 const float* __restrict__ bias_v,
                                                 float* __restrict__ b_ij,
                                                 short* __restrict__ c_wT,
                                                 float* __restrict__ csum_p,
                                                 int first) {
    __shared__ short cw_sh[Cn * 68];
    __shared__ float cs_sh[4][Cn];
    int lt = blockIdx.x, b = blockIdx.y;
    int t = threadIdx.x, w = t >> 6, lane = t & 63;
    int l15 = lane & 15, lg = lane >> 4;
    int l0 = lt * 64;
    f32x4 acc0 = {0.f, 0.f, 0.f, 0.f}, acc1 = {0.f, 0.f, 0.f, 0.f};
    const short* Ap = in_bf + ((size_t)b * Ln + l0 + w * 16 + l15) * Dn;
    const short* Bp = w_v + (size_t)b * Cn * Dn;
    for (int ks = 0; ks < 32; ++ks) {
        int koff = ks * 32 + lg * 8;
        bf16x8 a = *(const bf16x8*)(Ap + koff);
        bf16x8 b0 = *(const bf16x8*)(Bp + (size_t)l15 * Dn + koff);
        bf16x8 b1 = *(const bf16x8*)(Bp + (size_t)(l15 + 16) * Dn + koff);
        acc0 = __builtin_amdgcn_mfma_f32_16x16x32_bf16(a, b0, acc0, 0, 0, 0);
        acc1 = __builtin_amdgcn_mfma_f32_16x16x32_bf16(a, b1, acc1, 0, 0, 0);
    }
    float bv0 = bias_v[b * Cn + l15];
    float bv1 = bias_v[b * Cn + l15 + 16];
    float csa0 = 0.f, csa1 = 0.f;
#pragma unroll
    for (int r = 0; r < 4; ++r) {
        int lrow = l0 + w * 16 + lg * 4 + r;
        size_t boff = ((size_t)b * Ln + lrow) * Cn;
        float d0 = acc0[r] + bv0, d1 = acc1[r] + bv1;
        if (!first) { d0 += b_ij[boff + l15]; d1 += b_ij[boff + l15 + 16]; }
        b_ij[boff + l15] = d0;
        b_ij[boff + l15 + 16] = d1;
        float m = fmaxf(d0, d1);
        m = fmaxf(m, __shfl_xor(m, 1, 64)); m = fmaxf(m, __shfl_xor(m, 2, 64));
        m = fmaxf(m, __shfl_xor(m, 4, 64)); m = fmaxf(m, __shfl_xor(m, 8, 64));
        float e0 = __expf(d0 - m), e1 = __expf(d1 - m);
        float sm = e0 + e1;
        sm += __shfl_xor(sm, 1, 64); sm += __shfl_xor(sm, 2, 64);
        sm += __shfl_xor(sm, 4, 64); sm += __shfl_xor(sm, 8, 64);
        float inv = 1.0f / sm;
        float cw0 = e0 * inv, cw1 = e1 * inv;
        csa0 += cw0; csa1 += cw1;
        int ll = w * 16 + lg * 4 + r;
        cw_sh[l15 * 68 + ll] = (short)f2bf(cw0);
        cw_sh[(l15 + 16) * 68 + ll] = (short)f2bf(cw1);
    }
    csa0 += __shfl_xor(csa0, 16, 64); csa0 += __shfl_xor(csa0, 32, 64);
    csa1 += __shfl_xor(csa1, 16, 64); csa1 += __shfl_xor(csa1, 32, 64);
    if (lg == 0) { cs_sh[w][l15] = csa0; cs_sh[w][l15 + 16] = csa1; }
    __syncthreads();
    if (t < Cn) {
        float s = cs_sh[0][t] + cs_sh[1][t] + cs_sh[2][t] + cs_sh[3][t];
        csum_p[((size_t)lt * Bn + b) * Cn + t] = s;
    }
    {
        int cc = t >> 3, slot = t & 7;
        bf16x8 vv;
#pragma unroll
        for (int j = 0; j < 8; ++j) vv[j] = cw_sh[cc * 68 + slot * 8 + j];
        *(bf16x8*)(c_wT + ((size_t)b * Cn + cc) * Ln + l0 + slot * 8) = vv;
    }
}

// ----------------------------------------- x_cb[c][b][d] = c_w^T @ in -------
// grid (8 dt, 64 b), 256 thr / 4 waves. Stages in_bf 64l x 128d chunks into
// LDS as u32 l-pairs [128 d][36 u32], XOR-chunk swizzled (writes 2-way/free,
// fragment ds_read_b128 2-way/free); MFMA k-order identical to in_T path.
__global__ __launch_bounds__(256) void k_xc_m(const short* __restrict__ in_bf,
                                              const short* __restrict__ c_wT,
                                              short* __restrict__ x_cb) {
    __shared__ unsigned tile[128 * 36];   // 18432 B
    int dt = blockIdx.x, b = blockIdx.y;
    int t = threadIdx.x, w = t >> 6, lane = t & 63;
    int l15 = lane & 15, lg = lane >> 4;
    f32x4 acc[2][2];
#pragma unroll
    for (int h = 0; h < 2; ++h)
#pragma unroll
        for (int dd = 0; dd < 2; ++dd) acc[h][dd] = {0.f, 0.f, 0.f, 0.f};
    const short* A = c_wT + (size_t)b * Cn * Ln;   // [c][l]

    for (int lc = 0; lc < 8; ++lc) {
        int l0 = lc * 64;
        if (lc) __syncthreads();
#pragma unroll
        for (int task = 0; task < 2; ++task) {
            int idx = t + 256 * task;          // 0..511
            int oct = idx & 15, lp = idx >> 4; // d-octet, l-pair
            const short* src = in_bf + ((size_t)b * Ln + l0 + 2 * lp) * Dn + dt * 128 + oct * 8;
            bf16x8 a0 = *(const bf16x8*)src;
            bf16x8 a1 = *(const bf16x8*)(src + Dn);
            int col = lp ^ ((oct & 7) << 2);
            unsigned* trow = &tile[(size_t)(oct * 8) * 36 + col];
#pragma unroll
            for (int k = 0; k < 8; ++k)
                trow[k * 36] = (unsigned)(unsigned short)a0[k] |
                               ((unsigned)(unsigned short)a1[k] << 16);
        }
        __syncthreads();
#pragma unroll
        for (int ks = 0; ks < 2; ++ks) {
            int koff = ks * 32 + lg * 8;       // l within chunk
            int q = ks * 4 + lg;               // u32 chunk index
            bf16x8 a0 = *(const bf16x8*)(A + (size_t)l15 * Ln + l0 + koff);
            bf16x8 a1 = *(const bf16x8*)(A + (size_t)(l15 + 16) * Ln + l0 + koff);
#pragma unroll
            for (int dd = 0; dd < 2; ++dd) {
                int dloc = w * 32 + dd * 16 + l15;
                int qs = q ^ ((dloc >> 3) & 7);
                bf16x8 bb = *(const bf16x8*)&tile[dloc * 36 + qs * 4];
                acc[0][dd] = __builtin_amdgcn_mfma_f32_16x16x32_bf16(a0, bb, acc[0][dd], 0, 0, 0);
                acc[1][dd] = __builtin_amdgcn_mfma_f32_16x16x32_bf16(a1, bb, acc[1][dd], 0, 0, 0);
            }
        }
    }
#pragma unroll
    for (int h = 0; h < 2; ++h)
#pragma unroll
        for (int dd = 0; dd < 2; ++dd)
#pragma unroll
            for (int r = 0; r < 4; ++r) {
                int c = 16 * h + lg * 4 + r;
                int d = dt * 128 + w * 32 + dd * 16 + l15;
                x_cb[((size_t)c * Bn + b) * Dn + d] = (short)f2bf(acc[h][dd][r]);
            }
}

// ---------------------------------------------------------------------------
extern "C" void kernel_launch(void* const* d_in, const int* in_sizes, int n_in,
                              void* d_out, int out_size, void* d_ws, size_t ws_size,
                              hipStream_t stream) {
    const float* in   = (const float*)d_in[0];
    const float* fc_w = (const float*)d_in[1];
    const float* fc_b = (const float*)d_in[2];
    float* out = (float*)d_out;

    char* p = (char*)d_ws;
    auto alloc = [&](size_t bytes) -> char* {
        char* r = p;
        p += (bytes + 255) & ~(size_t)255;
        return r;
    };
    short* in_bf  = (short*)alloc((size_t)Bn * Ln * Dn * 2);   // 64 MB
    short* fc_wT  = (short*)alloc((size_t)COn * Dn * 2);       // 4 MB
    short* fc_wb  = (short*)alloc((size_t)COn * Dn * 2);       // 4 MB
    short* w_vb   = (short*)alloc((size_t)Bn * Cn * Dn * 2);   // 4 MB
    short* c_wT   = (short*)alloc((size_t)Bn * Cn * Ln * 2);   // 2 MB
    short* x_cb   = (short*)alloc((size_t)Cn * Bn * Dn * 2);   // 4 MB
    short* v_bf   = (short*)alloc((size_t)Bn * Cn * On * 2);   // 256 KB
    float* rs_p   = (float*)alloc((size_t)Bn * 8 * Dn * 4);    // 2 MB
    unsigned short* rs_bf = (unsigned short*)alloc((size_t)Bn * Dn * 2);
    float* b_ij   = (float*)alloc((size_t)Bn * Ln * Cn * 4);   // 4 MB
    float* bias_v = (float*)alloc((size_t)Bn * Cn * 4);
    float* csum_p = (float*)alloc((size_t)8 * Bn * Cn * 4);

    k_ctr<<<dim3(32, Bn), 256, 0, stream>>>(in, in_bf, rs_p);
    k_wprep<<<dim3(16, 8), 256, 0, stream>>>(fc_w, fc_wT, fc_wb);
    k_rsred<<<dim3(4, Bn), 256, 0, stream>>>(rs_p, rs_bf);
    k_sv3<<<Cn, 256, 0, stream>>>((const short*)rs_bf, csum_p, fc_wT, fc_b,
                                  v_bf, nullptr, bias_v, 1);
    for (int it = 1; it <= 2; ++it) {
        k_wv_m<<<dim3(4, Cn), 256, 0, stream>>>(fc_wb, v_bf, w_vb);
        k_route_m<<<dim3(8, Bn), 256, 0, stream>>>(in_bf, w_vb, bias_v, b_ij,
                                                   c_wT, csum_p, (it == 1) ? 1 : 0);
        k_xc_m<<<dim3(8, Bn), 256, 0, stream>>>(in_bf, c_wT, x_cb);
        k_sv3<<<Cn, 256, 0, stream>>>(x_cb, csum_p, fc_wT, fc_b,
                                      v_bf, (it == 2) ? out : nullptr, bias_v, 0);
    }
}

// Round 10
// 217.863 us; speedup vs baseline: 1.1665x; 1.0356x over previous
//
#include <hip/hip_runtime.h>

// CapsuleLayer: B=64, L=512, D=1024, C=32, O=64, 3 routing iters.
// u_hat never materialized:
//   dots[b,l,c] = in[b,l,:]@w_v[b,c,:] + bias_v[b,c]   (w_v[b,c,d] = sum_o fc_w[d,cO+o] v[b,c,o])
//   s_j[b,c,:]  = x_c[b,c,:]@fc_w[:,c,:] + csum[b,c]*fc_b[c,:]   (x_c = sum_l c_w * in)
// All contractions via mfma_f32_16x16x32_bf16. Single bf16 input copy
// in_bf[b][l][d]; k_xc_m stages l-contiguous B-fragments through LDS
// (u32 l-pair pack, XOR-chunk swizzle) with a T14 async-stage pipeline:
// global loads for chunk lc+1 issue during chunk lc's MFMA compute.

namespace {
constexpr int Bn = 64, Ln = 512, Dn = 1024, Cn = 32, On = 64, COn = Cn * On;
}

typedef float f32x4 __attribute__((ext_vector_type(4)));
typedef short bf16x8 __attribute__((ext_vector_type(8)));

static __device__ __forceinline__ unsigned f2bf(float f) {
    unsigned u = __float_as_uint(f);
    u += 0x7fff + ((u >> 16) & 1);   // RNE
    return u >> 16;
}

// ------------------------------------------------------------ conv ----------
// One pass over in fp32 [b][l][d], 64 l x 256 d per block; lane owns
// 8l x 8d micro-tile. No LDS. Emits in_bf + rowsum partials only.
__global__ __launch_bounds__(256) void k_ctr(const float* __restrict__ in,
                                             short* __restrict__ in_bf,
                                             float* __restrict__ rs_p) {
    int b = blockIdx.y;
    int lc = blockIdx.x >> 2, ds = blockIdx.x & 3;
    int l0 = lc * 64, d0 = ds * 256;
    int t = threadIdx.x, w = t >> 6, lane = t & 63;
    int db = lane & 7, lb = lane >> 3;
    int dloc = w * 64 + db * 8;
    int lloc = lb * 8;

    const float* src = in + ((size_t)b * Ln + l0 + lloc) * Dn + d0 + dloc;
    float4 ld[8][2];
#pragma unroll
    for (int r = 0; r < 8; ++r) {
        ld[r][0] = *(const float4*)(src + (size_t)r * Dn);
        ld[r][1] = *(const float4*)(src + (size_t)r * Dn + 4);
    }
    unsigned mr[8][4];
    float s[8];
#pragma unroll
    for (int k = 0; k < 8; ++k) s[k] = 0.f;
#pragma unroll
    for (int r = 0; r < 8; ++r) {
        const float* e = (const float*)&ld[r][0];
#pragma unroll
        for (int j = 0; j < 4; ++j)
            mr[r][j] = f2bf(e[2 * j]) | (f2bf(e[2 * j + 1]) << 16);
#pragma unroll
        for (int k = 0; k < 8; ++k) s[k] += e[k];
    }
    short* dbf = in_bf + ((size_t)b * Ln + l0 + lloc) * Dn + d0 + dloc;
#pragma unroll
    for (int r = 0; r < 8; ++r)
        *(uint4*)(dbf + (size_t)r * Dn) = make_uint4(mr[r][0], mr[r][1], mr[r][2], mr[r][3]);
#pragma unroll
    for (int k = 0; k < 8; ++k) {
        s[k] += __shfl_xor(s[k], 8, 64);
        s[k] += __shfl_xor(s[k], 16, 64);
        s[k] += __shfl_xor(s[k], 32, 64);
    }
    if (lb == 0) {
        float* rp = rs_p + ((size_t)b * 8 + lc) * Dn + d0 + dloc;
        *(float4*)rp = make_float4(s[0], s[1], s[2], s[3]);
        *(float4*)(rp + 4) = make_float4(s[4], s[5], s[6], s[7]);
    }
}

// -------------------------------------------------------- wprep + rsred -----
// blocks [0,128): fc_w fp32 [d][co] -> fc_wT bf16 [co][d] + fc_wb bf16 [d][co]
// blocks [128,384): rsred — rs_p partials -> rs_bf (/32, bf16)
__global__ __launch_bounds__(256) void k_prep2(const float* __restrict__ fc_w,
                                               short* __restrict__ fc_wT,
                                               short* __restrict__ fc_wb,
                                               const float* __restrict__ rs_p,
                                               unsigned short* __restrict__ rs_bf) {
    __shared__ short tr[64 * 260];      // used by wprep blocks only
    int t = threadIdx.x;
    if (blockIdx.x < 128) {
        int id = blockIdx.x;
        int d0 = (id & 15) * 64;
        int co0 = (id >> 4) * 256;
        int grp = t >> 6, cq = t & 63;
#pragma unroll
        for (int i = 0; i < 16; ++i) {
            int row = grp + 4 * i;
            float4 x = *(const float4*)(fc_w + (size_t)(d0 + row) * COn + co0 + cq * 4);
            short4 s4 = make_short4((short)f2bf(x.x), (short)f2bf(x.y),
                                    (short)f2bf(x.z), (short)f2bf(x.w));
            *(short4*)(&tr[row * 260 + cq * 4]) = s4;
            *(short4*)(fc_wb + (size_t)(d0 + row) * COn + co0 + cq * 4) = s4;
        }
        __syncthreads();
#pragma unroll
        for (int i = 0; i < 8; ++i) {
            int idx = t + 256 * i;
            int corow = idx >> 3, slot = idx & 7;
            bf16x8 v;
#pragma unroll
            for (int j = 0; j < 8; ++j) v[j] = tr[(slot * 8 + j) * 260 + corow];
            *(bf16x8*)(fc_wT + (size_t)(co0 + corow) * Dn + d0 + slot * 8) = v;
        }
    } else {
        int id = blockIdx.x - 128;      // 0..255
        int b = id >> 2, dq = id & 3;
        int d = dq * 256 + t;
        float s = 0.f;
#pragma unroll
        for (int lc = 0; lc < 8; ++lc) s += rs_p[((size_t)b * 8 + lc) * Dn + d];
        rs_bf[b * Dn + d] = (unsigned short)f2bf(s * (1.0f / 32.0f));
    }
}

// ------------------------------------------------------- s -> squash -> v ---
// Per-c MFMA GEMM: S[64 b][64 o] = X(64x1024)@W_c(1024x64).
__global__ __launch_bounds__(256) void k_sv3(const short* __restrict__ xA,
                                             const float* __restrict__ csum_p,
                                             const short* __restrict__ fc_wT,
                                             const float* __restrict__ fc_b,
                                             short* __restrict__ v_bf,
                                             float* __restrict__ fout,
                                             float* __restrict__ bias_v,
                                             int mode0) {
    int c = blockIdx.x;
    int t = threadIdx.x, w = t >> 6, lane = t & 63;
    int l15 = lane & 15, lg = lane >> 4;
    const short* A = mode0 ? xA : (xA + (size_t)c * Bn * Dn);   // [b][d]
    const short* Bw = fc_wT + (size_t)c * On * Dn;              // [o][d]
    f32x4 acc[4];
#pragma unroll
    for (int i = 0; i < 4; ++i) acc[i] = {0.f, 0.f, 0.f, 0.f};
#pragma unroll 2
    for (int ks = 0; ks < 32; ++ks) {
        int koff = ks * 32 + lg * 8;
        bf16x8 a = *(const bf16x8*)(A + (size_t)(w * 16 + l15) * Dn + koff);
#pragma unroll
        for (int dt = 0; dt < 4; ++dt) {
            bf16x8 bbf = *(const bf16x8*)(Bw + (size_t)(dt * 16 + l15) * Dn + koff);
            acc[dt] = __builtin_amdgcn_mfma_f32_16x16x32_bf16(a, bbf, acc[dt], 0, 0, 0);
        }
    }
    float fb[4];
#pragma unroll
    for (int dt = 0; dt < 4; ++dt) fb[dt] = fc_b[c * On + dt * 16 + l15];
#pragma unroll
    for (int r = 0; r < 4; ++r) {
        int brow = w * 16 + lg * 4 + r;
        float cs;
        if (mode0) {
            cs = 16.0f;
        } else {
            cs = 0.f;
#pragma unroll
            for (int lt = 0; lt < 8; ++lt) cs += csum_p[((size_t)lt * Bn + brow) * Cn + c];
        }
        float s0 = acc[0][r] + cs * fb[0];
        float s1 = acc[1][r] + cs * fb[1];
        float s2 = acc[2][r] + cs * fb[2];
        float s3 = acc[3][r] + cs * fb[3];
        float sq = s0 * s0 + s1 * s1 + s2 * s2 + s3 * s3;
        sq += __shfl_xor(sq, 1, 64); sq += __shfl_xor(sq, 2, 64);
        sq += __shfl_xor(sq, 4, 64); sq += __shfl_xor(sq, 8, 64);
        float scale = sq / (1.0f + sq) * rsqrtf(sq + 1e-8f);
        float v0 = scale * s0, v1 = scale * s1, v2 = scale * s2, v3 = scale * s3;
        size_t vo = ((size_t)brow * Cn + c) * On;
        v_bf[vo + 0 * 16 + l15] = (short)f2bf(v0);
        v_bf[vo + 1 * 16 + l15] = (short)f2bf(v1);
        v_bf[vo + 2 * 16 + l15] = (short)f2bf(v2);
        v_bf[vo + 3 * 16 + l15] = (short)f2bf(v3);
        if (fout) {
            fout[vo + 0 * 16 + l15] = v0;
            fout[vo + 1 * 16 + l15] = v1;
            fout[vo + 2 * 16 + l15] = v2;
            fout[vo + 3 * 16 + l15] = v3;
        }
        float bv = fb[0] * v0 + fb[1] * v1 + fb[2] * v2 + fb[3] * v3;
        bv += __shfl_xor(bv, 1, 64); bv += __shfl_xor(bv, 2, 64);
        bv += __shfl_xor(bv, 4, 64); bv += __shfl_xor(bv, 8, 64);
        if (l15 == 0) bias_v[brow * Cn + c] = bv;
    }
}

// ------------------------------------------- w_v via MFMA (contract o=64) ---
// grid (4 dslab, 32 c), 256 thr / 4 waves; wave: 64 d x 64 b, K=64.
__global__ __launch_bounds__(256) void k_wv_m(const short* __restrict__ fc_wb,
                                              const short* __restrict__ v_bf,
                                              short* __restrict__ w_vb) {
    int dsl = blockIdx.x, c = blockIdx.y;
    int t = threadIdx.x, w = t >> 6, lane = t & 63;
    int l15 = lane & 15, lg = lane >> 4;
    int dbase = dsl * 256 + w * 64;
    f32x4 acc[4][4];
#pragma unroll
    for (int i = 0; i < 4; ++i)
#pragma unroll
        for (int j = 0; j < 4; ++j) acc[i][j] = {0.f, 0.f, 0.f, 0.f};
#pragma unroll
    for (int ks = 0; ks < 2; ++ks) {
        int o = ks * 32 + lg * 8;
        bf16x8 bfr[4];
#pragma unroll
        for (int nt = 0; nt < 4; ++nt)
            bfr[nt] = *(const bf16x8*)(v_bf + ((size_t)(nt * 16 + l15) * Cn + c) * On + o);
#pragma unroll
        for (int mt = 0; mt < 4; ++mt) {
            bf16x8 a = *(const bf16x8*)(fc_wb + (size_t)(dbase + mt * 16 + l15) * COn + c * On + o);
#pragma unroll
            for (int nt = 0; nt < 4; ++nt)
                acc[mt][nt] = __builtin_amdgcn_mfma_f32_16x16x32_bf16(a, bfr[nt], acc[mt][nt], 0, 0, 0);
        }
    }
#pragma unroll
    for (int mt = 0; mt < 4; ++mt)
#pragma unroll
        for (int nt = 0; nt < 4; ++nt) {
            int bb = nt * 16 + l15;
            int d = dbase + mt * 16 + lg * 4;
            *(short4*)(w_vb + ((size_t)bb * Cn + c) * Dn + d) =
                make_short4((short)f2bf(acc[mt][nt][0]), (short)f2bf(acc[mt][nt][1]),
                            (short)f2bf(acc[mt][nt][2]), (short)f2bf(acc[mt][nt][3]));
        }
}

// ------------------------------- dots -> b_ij update -> softmax -> c_wT -----
// grid (8 lt, 64 b), 256 thr / 4 waves, wave = 16 l-rows x 32 c. MFMA,
// A-frags straight from in_bf (bf16), B = w_v bf16 rows. ks-loop unrolled 4
// so the scheduler keeps ~12 loads in flight (2 blocks/CU -> TLP is thin).
__global__ __launch_bounds__(256) void k_route_m(const short* __restrict__ in_bf,
                                                 const short* __restrict__ w_v,
                                                 const float* __restrict__ bias_v,
                                                 float* __restrict__ b_ij,
                                                 short* __restrict__ c_wT,
                                                 float* __restrict__ csum_p,
                                                 int first) {
    __shared__ short cw_sh[Cn * 68];
    __shared__ float cs_sh[4][Cn];
    int lt = blockIdx.x, b = blockIdx.y;
    int t = threadIdx.x, w = t >> 6, lane = t & 63;
    int l15 = lane & 15, lg = lane >> 4;
    int l0 = lt * 64;
    f32x4 acc0 = {0.f, 0.f, 0.f, 0.f}, acc1 = {0.f, 0.f, 0.f, 0.f};
    const short* Ap = in_bf + ((size_t)b * Ln + l0 + w * 16 + l15) * Dn;
    const short* Bp = w_v + (size_t)b * Cn * Dn;
#pragma unroll 4
    for (int ks = 0; ks < 32; ++ks) {
        int koff = ks * 32 + lg * 8;
        bf16x8 a = *(const bf16x8*)(Ap + koff);
        bf16x8 b0 = *(const bf16x8*)(Bp + (size_t)l15 * Dn + koff);
        bf16x8 b1 = *(const bf16x8*)(Bp + (size_t)(l15 + 16) * Dn + koff);
        acc0 = __builtin_amdgcn_mfma_f32_16x16x32_bf16(a, b0, acc0, 0, 0, 0);
        acc1 = __builtin_amdgcn_mfma_f32_16x16x32_bf16(a, b1, acc1, 0, 0, 0);
    }
    float bv0 = bias_v[b * Cn + l15];
    float bv1 = bias_v[b * Cn + l15 + 16];
    float csa0 = 0.f, csa1 = 0.f;
#pragma unroll
    for (int r = 0; r < 4; ++r) {
        int lrow = l0 + w * 16 + lg * 4 + r;
        size_t boff = ((size_t)b * Ln + lrow) * Cn;
        float d0 = acc0[r] + bv0, d1 = acc1[r] + bv1;
        if (!first) { d0 += b_ij[boff + l15]; d1 += b_ij[boff + l15 + 16]; }
        b_ij[boff + l15] = d0;
        b_ij[boff + l15 + 16] = d1;
        float m = fmaxf(d0, d1);
        m = fmaxf(m, __shfl_xor(m, 1, 64)); m = fmaxf(m, __shfl_xor(m, 2, 64));
        m = fmaxf(m, __shfl_xor(m, 4, 64)); m = fmaxf(m, __shfl_xor(m, 8, 64));
        float e0 = __expf(d0 - m), e1 = __expf(d1 - m);
        float sm = e0 + e1;
        sm += __shfl_xor(sm, 1, 64); sm += __shfl_xor(sm, 2, 64);
        sm += __shfl_xor(sm, 4, 64); sm += __shfl_xor(sm, 8, 64);
        float inv = 1.0f / sm;
        float cw0 = e0 * inv, cw1 = e1 * inv;
        csa0 += cw0; csa1 += cw1;
        int ll = w * 16 + lg * 4 + r;
        cw_sh[l15 * 68 + ll] = (short)f2bf(cw0);
        cw_sh[(l15 + 16) * 68 + ll] = (short)f2bf(cw1);
    }
    csa0 += __shfl_xor(csa0, 16, 64); csa0 += __shfl_xor(csa0, 32, 64);
    csa1 += __shfl_xor(csa1, 16, 64); csa1 += __shfl_xor(csa1, 32, 64);
    if (lg == 0) { cs_sh[w][l15] = csa0; cs_sh[w][l15 + 16] = csa1; }
    __syncthreads();
    if (t < Cn) {
        float s = cs_sh[0][t] + cs_sh[1][t] + cs_sh[2][t] + cs_sh[3][t];
        csum_p[((size_t)lt * Bn + b) * Cn + t] = s;
    }
    {
        int cc = t >> 3, slot = t & 7;
        bf16x8 vv;
#pragma unroll
        for (int j = 0; j < 8; ++j) vv[j] = cw_sh[cc * 68 + slot * 8 + j];
        *(bf16x8*)(c_wT + ((size_t)b * Cn + cc) * Ln + l0 + slot * 8) = vv;
    }
}

// ----------------------------------------- x_cb[c][b][d] = c_w^T @ in -------
// grid (8 dt, 64 b), 256 thr / 4 waves. T14 async-stage pipeline: global
// loads (in_bf micro-tile + c_wT A-frags) for chunk lc+1 issue right after
// the first barrier, hiding HBM/L3 latency under chunk lc's MFMA compute.
// LDS: [128 d][36 u32] l-pair pack, XOR-chunk swizzle (2-way/free both ways).
__global__ __launch_bounds__(256) void k_xc_m(const short* __restrict__ in_bf,
                                              const short* __restrict__ c_wT,
                                              short* __restrict__ x_cb) {
    __shared__ unsigned tile[128 * 36];   // 18432 B
    int dt = blockIdx.x, b = blockIdx.y;
    int t = threadIdx.x, w = t >> 6, lane = t & 63;
    int l15 = lane & 15, lg = lane >> 4;
    f32x4 acc[2][2];
#pragma unroll
    for (int h = 0; h < 2; ++h)
#pragma unroll
        for (int dd = 0; dd < 2; ++dd) acc[h][dd] = {0.f, 0.f, 0.f, 0.f};
    const short* A = c_wT + (size_t)b * Cn * Ln;   // [c][l]

    // staging ownership: oct = d-octet, two l-pairs per thread (lpA, lpA+16)
    int oct = t & 15, lpA = t >> 4, lpB = lpA + 16;
    const short* gbase = in_bf + (size_t)b * Ln * Dn + dt * 128 + oct * 8;
    int colA = lpA ^ ((oct & 7) << 2);
    int colB = lpB ^ ((oct & 7) << 2);
    unsigned* trow = &tile[(oct * 8) * 36];

    bf16x8 ra0, ra1, rb0, rb1;              // staged in_bf micro-rows
    bf16x8 a0c[2], a1c[2], a0n[2], a1n[2];  // A-fragments, cur/next

#define XC_LOADG(LC)                                                          \
    {                                                                         \
        const short* sA = gbase + (size_t)((LC) * 64 + 2 * lpA) * Dn;         \
        const short* sB = gbase + (size_t)((LC) * 64 + 2 * lpB) * Dn;         \
        ra0 = *(const bf16x8*)sA; ra1 = *(const bf16x8*)(sA + Dn);            \
        rb0 = *(const bf16x8*)sB; rb1 = *(const bf16x8*)(sB + Dn);            \
    }
#define XC_LOADA(LC, D0, D1)                                                  \
    _Pragma("unroll")                                                         \
    for (int ks = 0; ks < 2; ++ks) {                                          \
        int off = (LC) * 64 + ks * 32 + lg * 8;                               \
        D0[ks] = *(const bf16x8*)(A + (size_t)l15 * Ln + off);                \
        D1[ks] = *(const bf16x8*)(A + (size_t)(l15 + 16) * Ln + off);         \
    }

    XC_LOADG(0);
    XC_LOADA(0, a0c, a1c);

    for (int lc = 0; lc < 8; ++lc) {
#pragma unroll
        for (int k = 0; k < 8; ++k) {
            trow[k * 36 + colA] = (unsigned)(unsigned short)ra0[k] |
                                  ((unsigned)(unsigned short)ra1[k] << 16);
            trow[k * 36 + colB] = (unsigned)(unsigned short)rb0[k] |
                                  ((unsigned)(unsigned short)rb1[k] << 16);
        }
        __syncthreads();
        if (lc < 7) {
            XC_LOADG(lc + 1);
            XC_LOADA(lc + 1, a0n, a1n);
        }
#pragma unroll
        for (int ks = 0; ks < 2; ++ks) {
            int q = ks * 4 + lg;               // u32 chunk index
#pragma unroll
            for (int dd = 0; dd < 2; ++dd) {
                int dloc = w * 32 + dd * 16 + l15;
                int qs = q ^ ((dloc >> 3) & 7);
                bf16x8 bb = *(const bf16x8*)&tile[dloc * 36 + qs * 4];
                acc[0][dd] = __builtin_amdgcn_mfma_f32_16x16x32_bf16(a0c[ks], bb, acc[0][dd], 0, 0, 0);
                acc[1][dd] = __builtin_amdgcn_mfma_f32_16x16x32_bf16(a1c[ks], bb, acc[1][dd], 0, 0, 0);
            }
        }
        __syncthreads();
        if (lc < 7) {
#pragma unroll
            for (int ks = 0; ks < 2; ++ks) { a0c[ks] = a0n[ks]; a1c[ks] = a1n[ks]; }
        }
    }
#undef XC_LOADG
#undef XC_LOADA
#pragma unroll
    for (int h = 0; h < 2; ++h)
#pragma unroll
        for (int dd = 0; dd < 2; ++dd)
#pragma unroll
            for (int r = 0; r < 4; ++r) {
                int c = 16 * h + lg * 4 + r;
                int d = dt * 128 + w * 32 + dd * 16 + l15;
                x_cb[((size_t)c * Bn + b) * Dn + d] = (short)f2bf(acc[h][dd][r]);
            }
}

// ---------------------------------------------------------------------------
extern "C" void kernel_launch(void* const* d_in, const int* in_sizes, int n_in,
                              void* d_out, int out_size, void* d_ws, size_t ws_size,
                              hipStream_t stream) {
    const float* in   = (const float*)d_in[0];
    const float* fc_w = (const float*)d_in[1];
    const float* fc_b = (const float*)d_in[2];
    float* out = (float*)d_out;

    char* p = (char*)d_ws;
    auto alloc = [&](size_t bytes) -> char* {
        char* r = p;
        p += (bytes + 255) & ~(size_t)255;
        return r;
    };
    short* in_bf  = (short*)alloc((size_t)Bn * Ln * Dn * 2);   // 64 MB
    short* fc_wT  = (short*)alloc((size_t)COn * Dn * 2);       // 4 MB
    short* fc_wb  = (short*)alloc((size_t)COn * Dn * 2);       // 4 MB
    short* w_vb   = (short*)alloc((size_t)Bn * Cn * Dn * 2);   // 4 MB
    short* c_wT   = (short*)alloc((size_t)Bn * Cn * Ln * 2);   // 2 MB
    short* x_cb   = (short*)alloc((size_t)Cn * Bn * Dn * 2);   // 4 MB
    short* v_bf   = (short*)alloc((size_t)Bn * Cn * On * 2);   // 256 KB
    float* rs_p   = (float*)alloc((size_t)Bn * 8 * Dn * 4);    // 2 MB
    unsigned short* rs_bf = (unsigned short*)alloc((size_t)Bn * Dn * 2);
    float* b_ij   = (float*)alloc((size_t)Bn * Ln * Cn * 4);   // 4 MB
    float* bias_v = (float*)alloc((size_t)Bn * Cn * 4);
    float* csum_p = (float*)alloc((size_t)8 * Bn * Cn * 4);

    k_ctr<<<dim3(32, Bn), 256, 0, stream>>>(in, in_bf, rs_p);
    k_prep2<<<384, 256, 0, stream>>>(fc_w, fc_wT, fc_wb, rs_p, rs_bf);
    k_sv3<<<Cn, 256, 0, stream>>>((const short*)rs_bf, csum_p, fc_wT, fc_b,
                                  v_bf, nullptr, bias_v, 1);
    for (int it = 1; it <= 2; ++it) {
        k_wv_m<<<dim3(4, Cn), 256, 0, stream>>>(fc_wb, v_bf, w_vb);
        k_route_m<<<dim3(8, Bn), 256, 0, stream>>>(in_bf, w_vb, bias_v, b_ij,
                                                   c_wT, csum_p, (it == 1) ? 1 : 0);
        k_xc_m<<<dim3(8, Bn), 256, 0, stream>>>(in_bf, c_wT, x_cb);
        k_sv3<<<Cn, 256, 0, stream>>>(x_cb, csum_p, fc_wT, fc_b,
                                      v_bf, (it == 2) ? out : nullptr, bias_v, 0);
    }
}

// Round 11
// 190.300 us; speedup vs baseline: 1.3355x; 1.1448x over previous
//
#include <hip/hip_runtime.h>

// CapsuleLayer: B=64, L=512, D=1024, C=32, O=64, 3 routing iters.
// u_hat never materialized:
//   dots[b,l,c] = in[b,l,:]@w_v[b,c,:] + bias_v[b,c]   (w_v[b,c,d] = sum_o fc_w[d,cO+o] v[b,c,o])
//   s_j[b,c,:]  = x_c[b,c,:]@fc_w[:,c,:] + csum[b,c]*fc_b[c,:]   (x_c = sum_l c_w * in)
// All contractions via mfma_f32_16x16x32_bf16. Single bf16 input copy
// in_bf[b][l][d]; k_xc_m stages l-contiguous B-fragments through LDS
// (u32 l-pair pack, XOR-chunk swizzle) with T14 async-stage pipeline.
// k_sv3: one-wave blocks, grid (4 b-tiles x 32 c) = 128 CUs (was 32 blocks).

namespace {
constexpr int Bn = 64, Ln = 512, Dn = 1024, Cn = 32, On = 64, COn = Cn * On;
}

typedef float f32x4 __attribute__((ext_vector_type(4)));
typedef short bf16x8 __attribute__((ext_vector_type(8)));

static __device__ __forceinline__ unsigned f2bf(float f) {
    unsigned u = __float_as_uint(f);
    u += 0x7fff + ((u >> 16) & 1);   // RNE
    return u >> 16;
}

// ------------------------------------------------------------ conv ----------
// One pass over in fp32 [b][l][d], 64 l x 256 d per block; lane owns
// 8l x 8d micro-tile. No LDS. Emits in_bf + rowsum partials only.
__global__ __launch_bounds__(256) void k_ctr(const float* __restrict__ in,
                                             short* __restrict__ in_bf,
                                             float* __restrict__ rs_p) {
    int b = blockIdx.y;
    int lc = blockIdx.x >> 2, ds = blockIdx.x & 3;
    int l0 = lc * 64, d0 = ds * 256;
    int t = threadIdx.x, w = t >> 6, lane = t & 63;
    int db = lane & 7, lb = lane >> 3;
    int dloc = w * 64 + db * 8;
    int lloc = lb * 8;

    const float* src = in + ((size_t)b * Ln + l0 + lloc) * Dn + d0 + dloc;
    float4 ld[8][2];
#pragma unroll
    for (int r = 0; r < 8; ++r) {
        ld[r][0] = *(const float4*)(src + (size_t)r * Dn);
        ld[r][1] = *(const float4*)(src + (size_t)r * Dn + 4);
    }
    unsigned mr[8][4];
    float s[8];
#pragma unroll
    for (int k = 0; k < 8; ++k) s[k] = 0.f;
#pragma unroll
    for (int r = 0; r < 8; ++r) {
        const float* e = (const float*)&ld[r][0];
#pragma unroll
        for (int j = 0; j < 4; ++j)
            mr[r][j] = f2bf(e[2 * j]) | (f2bf(e[2 * j + 1]) << 16);
#pragma unroll
        for (int k = 0; k < 8; ++k) s[k] += e[k];
    }
    short* dbf = in_bf + ((size_t)b * Ln + l0 + lloc) * Dn + d0 + dloc;
#pragma unroll
    for (int r = 0; r < 8; ++r)
        *(uint4*)(dbf + (size_t)r * Dn) = make_uint4(mr[r][0], mr[r][1], mr[r][2], mr[r][3]);
#pragma unroll
    for (int k = 0; k < 8; ++k) {
        s[k] += __shfl_xor(s[k], 8, 64);
        s[k] += __shfl_xor(s[k], 16, 64);
        s[k] += __shfl_xor(s[k], 32, 64);
    }
    if (lb == 0) {
        float* rp = rs_p + ((size_t)b * 8 + lc) * Dn + d0 + dloc;
        *(float4*)rp = make_float4(s[0], s[1], s[2], s[3]);
        *(float4*)(rp + 4) = make_float4(s[4], s[5], s[6], s[7]);
    }
}

// -------------------------------------------------------- wprep + rsred -----
// blocks [0,128): fc_w fp32 [d][co] -> fc_wT bf16 [co][d] + fc_wb bf16 [d][co]
// blocks [128,384): rsred — rs_p partials -> rs_bf (/32, bf16)
__global__ __launch_bounds__(256) void k_prep2(const float* __restrict__ fc_w,
                                               short* __restrict__ fc_wT,
                                               short* __restrict__ fc_wb,
                                               const float* __restrict__ rs_p,
                                               unsigned short* __restrict__ rs_bf) {
    __shared__ short tr[64 * 260];      // used by wprep blocks only
    int t = threadIdx.x;
    if (blockIdx.x < 128) {
        int id = blockIdx.x;
        int d0 = (id & 15) * 64;
        int co0 = (id >> 4) * 256;
        int grp = t >> 6, cq = t & 63;
#pragma unroll
        for (int i = 0; i < 16; ++i) {
            int row = grp + 4 * i;
            float4 x = *(const float4*)(fc_w + (size_t)(d0 + row) * COn + co0 + cq * 4);
            short4 s4 = make_short4((short)f2bf(x.x), (short)f2bf(x.y),
                                    (short)f2bf(x.z), (short)f2bf(x.w));
            *(short4*)(&tr[row * 260 + cq * 4]) = s4;
            *(short4*)(fc_wb + (size_t)(d0 + row) * COn + co0 + cq * 4) = s4;
        }
        __syncthreads();
#pragma unroll
        for (int i = 0; i < 8; ++i) {
            int idx = t + 256 * i;
            int corow = idx >> 3, slot = idx & 7;
            bf16x8 v;
#pragma unroll
            for (int j = 0; j < 8; ++j) v[j] = tr[(slot * 8 + j) * 260 + corow];
            *(bf16x8*)(fc_wT + (size_t)(co0 + corow) * Dn + d0 + slot * 8) = v;
        }
    } else {
        int id = blockIdx.x - 128;      // 0..255
        int b = id >> 2, dq = id & 3;
        int d = dq * 256 + t;
        float s = 0.f;
#pragma unroll
        for (int lc = 0; lc < 8; ++lc) s += rs_p[((size_t)b * 8 + lc) * Dn + d];
        rs_bf[b * Dn + d] = (unsigned short)f2bf(s * (1.0f / 32.0f));
    }
}

// ------------------------------------------------------- s -> squash -> v ---
// Per-(btile,c) MFMA GEMM: one wave computes S[16 b][64 o]. Grid (4, 32),
// 64-thread blocks -> 128 CUs active (was 32 blocks / 32 CUs).
__global__ __launch_bounds__(64) void k_sv3(const short* __restrict__ xA,
                                            const float* __restrict__ csum_p,
                                            const short* __restrict__ fc_wT,
                                            const float* __restrict__ fc_b,
                                            short* __restrict__ v_bf,
                                            float* __restrict__ fout,
                                            float* __restrict__ bias_v,
                                            int mode0) {
    int w = blockIdx.x;                 // b-tile 0..3
    int c = blockIdx.y;
    int lane = threadIdx.x;             // 0..63
    int l15 = lane & 15, lg = lane >> 4;
    const short* A = mode0 ? xA : (xA + (size_t)c * Bn * Dn);   // [b][d]
    const short* Bw = fc_wT + (size_t)c * On * Dn;              // [o][d]
    f32x4 acc[4];
#pragma unroll
    for (int i = 0; i < 4; ++i) acc[i] = {0.f, 0.f, 0.f, 0.f};
#pragma unroll 4
    for (int ks = 0; ks < 32; ++ks) {
        int koff = ks * 32 + lg * 8;
        bf16x8 a = *(const bf16x8*)(A + (size_t)(w * 16 + l15) * Dn + koff);
#pragma unroll
        for (int dt = 0; dt < 4; ++dt) {
            bf16x8 bbf = *(const bf16x8*)(Bw + (size_t)(dt * 16 + l15) * Dn + koff);
            acc[dt] = __builtin_amdgcn_mfma_f32_16x16x32_bf16(a, bbf, acc[dt], 0, 0, 0);
        }
    }
    float fb[4];
#pragma unroll
    for (int dt = 0; dt < 4; ++dt) fb[dt] = fc_b[c * On + dt * 16 + l15];
#pragma unroll
    for (int r = 0; r < 4; ++r) {
        int brow = w * 16 + lg * 4 + r;
        float cs;
        if (mode0) {
            cs = 16.0f;
        } else {
            cs = 0.f;
#pragma unroll
            for (int lt = 0; lt < 8; ++lt) cs += csum_p[((size_t)lt * Bn + brow) * Cn + c];
        }
        float s0 = acc[0][r] + cs * fb[0];
        float s1 = acc[1][r] + cs * fb[1];
        float s2 = acc[2][r] + cs * fb[2];
        float s3 = acc[3][r] + cs * fb[3];
        float sq = s0 * s0 + s1 * s1 + s2 * s2 + s3 * s3;
        sq += __shfl_xor(sq, 1, 64); sq += __shfl_xor(sq, 2, 64);
        sq += __shfl_xor(sq, 4, 64); sq += __shfl_xor(sq, 8, 64);
        float scale = sq / (1.0f + sq) * rsqrtf(sq + 1e-8f);
        float v0 = scale * s0, v1 = scale * s1, v2 = scale * s2, v3 = scale * s3;
        size_t vo = ((size_t)brow * Cn + c) * On;
        v_bf[vo + 0 * 16 + l15] = (short)f2bf(v0);
        v_bf[vo + 1 * 16 + l15] = (short)f2bf(v1);
        v_bf[vo + 2 * 16 + l15] = (short)f2bf(v2);
        v_bf[vo + 3 * 16 + l15] = (short)f2bf(v3);
        if (fout) {
            fout[vo + 0 * 16 + l15] = v0;
            fout[vo + 1 * 16 + l15] = v1;
            fout[vo + 2 * 16 + l15] = v2;
            fout[vo + 3 * 16 + l15] = v3;
        }
        float bv = fb[0] * v0 + fb[1] * v1 + fb[2] * v2 + fb[3] * v3;
        bv += __shfl_xor(bv, 1, 64); bv += __shfl_xor(bv, 2, 64);
        bv += __shfl_xor(bv, 4, 64); bv += __shfl_xor(bv, 8, 64);
        if (l15 == 0) bias_v[brow * Cn + c] = bv;
    }
}

// ------------------------------------------- w_v via MFMA (contract o=64) ---
// grid (4 dslab, 32 c), 256 thr / 4 waves; wave: 64 d x 64 b, K=64.
__global__ __launch_bounds__(256) void k_wv_m(const short* __restrict__ fc_wb,
                                              const short* __restrict__ v_bf,
                                              short* __restrict__ w_vb) {
    int dsl = blockIdx.x, c = blockIdx.y;
    int t = threadIdx.x, w = t >> 6, lane = t & 63;
    int l15 = lane & 15, lg = lane >> 4;
    int dbase = dsl * 256 + w * 64;
    f32x4 acc[4][4];
#pragma unroll
    for (int i = 0; i < 4; ++i)
#pragma unroll
        for (int j = 0; j < 4; ++j) acc[i][j] = {0.f, 0.f, 0.f, 0.f};
#pragma unroll
    for (int ks = 0; ks < 2; ++ks) {
        int o = ks * 32 + lg * 8;
        bf16x8 bfr[4];
#pragma unroll
        for (int nt = 0; nt < 4; ++nt)
            bfr[nt] = *(const bf16x8*)(v_bf + ((size_t)(nt * 16 + l15) * Cn + c) * On + o);
#pragma unroll
        for (int mt = 0; mt < 4; ++mt) {
            bf16x8 a = *(const bf16x8*)(fc_wb + (size_t)(dbase + mt * 16 + l15) * COn + c * On + o);
#pragma unroll
            for (int nt = 0; nt < 4; ++nt)
                acc[mt][nt] = __builtin_amdgcn_mfma_f32_16x16x32_bf16(a, bfr[nt], acc[mt][nt], 0, 0, 0);
        }
    }
#pragma unroll
    for (int mt = 0; mt < 4; ++mt)
#pragma unroll
        for (int nt = 0; nt < 4; ++nt) {
            int bb = nt * 16 + l15;
            int d = dbase + mt * 16 + lg * 4;
            *(short4*)(w_vb + ((size_t)bb * Cn + c) * Dn + d) =
                make_short4((short)f2bf(acc[mt][nt][0]), (short)f2bf(acc[mt][nt][1]),
                            (short)f2bf(acc[mt][nt][2]), (short)f2bf(acc[mt][nt][3]));
        }
}

// ------------------------------- dots -> b_ij update -> softmax -> c_wT -----
// grid (8 lt, 64 b), 256 thr / 4 waves, wave = 16 l-rows x 32 c. MFMA,
// A-frags straight from in_bf (bf16), B = w_v bf16 rows. last=1 skips the
// dead b_ij store on the final iteration.
__global__ __launch_bounds__(256) void k_route_m(const short* __restrict__ in_bf,
                                                 const short* __restrict__ w_v,
                                                 const float* __restrict__ bias_v,
                                                 float* __restrict__ b_ij,
                                                 short* __restrict__ c_wT,
                                                 float* __restrict__ csum_p,
                                                 int first, int last) {
    __shared__ short cw_sh[Cn * 68];
    __shared__ float cs_sh[4][Cn];
    int lt = blockIdx.x, b = blockIdx.y;
    int t = threadIdx.x, w = t >> 6, lane = t & 63;
    int l15 = lane & 15, lg = lane >> 4;
    int l0 = lt * 64;
    f32x4 acc0 = {0.f, 0.f, 0.f, 0.f}, acc1 = {0.f, 0.f, 0.f, 0.f};
    const short* Ap = in_bf + ((size_t)b * Ln + l0 + w * 16 + l15) * Dn;
    const short* Bp = w_v + (size_t)b * Cn * Dn;
#pragma unroll 4
    for (int ks = 0; ks < 32; ++ks) {
        int koff = ks * 32 + lg * 8;
        bf16x8 a = *(const bf16x8*)(Ap + koff);
        bf16x8 b0 = *(const bf16x8*)(Bp + (size_t)l15 * Dn + koff);
        bf16x8 b1 = *(const bf16x8*)(Bp + (size_t)(l15 + 16) * Dn + koff);
        acc0 = __builtin_amdgcn_mfma_f32_16x16x32_bf16(a, b0, acc0, 0, 0, 0);
        acc1 = __builtin_amdgcn_mfma_f32_16x16x32_bf16(a, b1, acc1, 0, 0, 0);
    }
    float bv0 = bias_v[b * Cn + l15];
    float bv1 = bias_v[b * Cn + l15 + 16];
    float csa0 = 0.f, csa1 = 0.f;
#pragma unroll
    for (int r = 0; r < 4; ++r) {
        int lrow = l0 + w * 16 + lg * 4 + r;
        size_t boff = ((size_t)b * Ln + lrow) * Cn;
        float d0 = acc0[r] + bv0, d1 = acc1[r] + bv1;
        if (!first) { d0 += b_ij[boff + l15]; d1 += b_ij[boff + l15 + 16]; }
        if (!last) {
            b_ij[boff + l15] = d0;
            b_ij[boff + l15 + 16] = d1;
        }
        float m = fmaxf(d0, d1);
        m = fmaxf(m, __shfl_xor(m, 1, 64)); m = fmaxf(m, __shfl_xor(m, 2, 64));
        m = fmaxf(m, __shfl_xor(m, 4, 64)); m = fmaxf(m, __shfl_xor(m, 8, 64));
        float e0 = __expf(d0 - m), e1 = __expf(d1 - m);
        float sm = e0 + e1;
        sm += __shfl_xor(sm, 1, 64); sm += __shfl_xor(sm, 2, 64);
        sm += __shfl_xor(sm, 4, 64); sm += __shfl_xor(sm, 8, 64);
        float inv = 1.0f / sm;
        float cw0 = e0 * inv, cw1 = e1 * inv;
        csa0 += cw0; csa1 += cw1;
        int ll = w * 16 + lg * 4 + r;
        cw_sh[l15 * 68 + ll] = (short)f2bf(cw0);
        cw_sh[(l15 + 16) * 68 + ll] = (short)f2bf(cw1);
    }
    csa0 += __shfl_xor(csa0, 16, 64); csa0 += __shfl_xor(csa0, 32, 64);
    csa1 += __shfl_xor(csa1, 16, 64); csa1 += __shfl_xor(csa1, 32, 64);
    if (lg == 0) { cs_sh[w][l15] = csa0; cs_sh[w][l15 + 16] = csa1; }
    __syncthreads();
    if (t < Cn) {
        float s = cs_sh[0][t] + cs_sh[1][t] + cs_sh[2][t] + cs_sh[3][t];
        csum_p[((size_t)lt * Bn + b) * Cn + t] = s;
    }
    {
        int cc = t >> 3, slot = t & 7;
        bf16x8 vv;
#pragma unroll
        for (int j = 0; j < 8; ++j) vv[j] = cw_sh[cc * 68 + slot * 8 + j];
        *(bf16x8*)(c_wT + ((size_t)b * Cn + cc) * Ln + l0 + slot * 8) = vv;
    }
}

// ----------------------------------------- x_cb[c][b][d] = c_w^T @ in -------
// grid (8 dt, 64 b), 256 thr / 4 waves. T14 async-stage pipeline: global
// loads (in_bf micro-tile + c_wT A-frags) for chunk lc+1 issue right after
// the first barrier, hiding HBM/L3 latency under chunk lc's MFMA compute.
// LDS: [128 d][36 u32] l-pair pack, XOR-chunk swizzle (2-way/free both ways).
__global__ __launch_bounds__(256) void k_xc_m(const short* __restrict__ in_bf,
                                              const short* __restrict__ c_wT,
                                              short* __restrict__ x_cb) {
    __shared__ unsigned tile[128 * 36];   // 18432 B
    int dt = blockIdx.x, b = blockIdx.y;
    int t = threadIdx.x, w = t >> 6, lane = t & 63;
    int l15 = lane & 15, lg = lane >> 4;
    f32x4 acc[2][2];
#pragma unroll
    for (int h = 0; h < 2; ++h)
#pragma unroll
        for (int dd = 0; dd < 2; ++dd) acc[h][dd] = {0.f, 0.f, 0.f, 0.f};
    const short* A = c_wT + (size_t)b * Cn * Ln;   // [c][l]

    // staging ownership: oct = d-octet, two l-pairs per thread (lpA, lpA+16)
    int oct = t & 15, lpA = t >> 4, lpB = lpA + 16;
    const short* gbase = in_bf + (size_t)b * Ln * Dn + dt * 128 + oct * 8;
    int colA = lpA ^ ((oct & 7) << 2);
    int colB = lpB ^ ((oct & 7) << 2);
    unsigned* trow = &tile[(oct * 8) * 36];

    bf16x8 ra0, ra1, rb0, rb1;              // staged in_bf micro-rows
    bf16x8 a0c[2], a1c[2], a0n[2], a1n[2];  // A-fragments, cur/next

#define XC_LOADG(LC)                                                          \
    {                                                                         \
        const short* sA = gbase + (size_t)((LC) * 64 + 2 * lpA) * Dn;         \
        const short* sB = gbase + (size_t)((LC) * 64 + 2 * lpB) * Dn;         \
        ra0 = *(const bf16x8*)sA; ra1 = *(const bf16x8*)(sA + Dn);            \
        rb0 = *(const bf16x8*)sB; rb1 = *(const bf16x8*)(sB + Dn);            \
    }
#define XC_LOADA(LC, D0, D1)                                                  \
    _Pragma("unroll")                                                         \
    for (int ks = 0; ks < 2; ++ks) {                                          \
        int off = (LC) * 64 + ks * 32 + lg * 8;                               \
        D0[ks] = *(const bf16x8*)(A + (size_t)l15 * Ln + off);                \
        D1[ks] = *(const bf16x8*)(A + (size_t)(l15 + 16) * Ln + off);         \
    }

    XC_LOADG(0);
    XC_LOADA(0, a0c, a1c);

    for (int lc = 0; lc < 8; ++lc) {
#pragma unroll
        for (int k = 0; k < 8; ++k) {
            trow[k * 36 + colA] = (unsigned)(unsigned short)ra0[k] |
                                  ((unsigned)(unsigned short)ra1[k] << 16);
            trow[k * 36 + colB] = (unsigned)(unsigned short)rb0[k] |
                                  ((unsigned)(unsigned short)rb1[k] << 16);
        }
        __syncthreads();
        if (lc < 7) {
            XC_LOADG(lc + 1);
            XC_LOADA(lc + 1, a0n, a1n);
        }
#pragma unroll
        for (int ks = 0; ks < 2; ++ks) {
            int q = ks * 4 + lg;               // u32 chunk index
#pragma unroll
            for (int dd = 0; dd < 2; ++dd) {
                int dloc = w * 32 + dd * 16 + l15;
                int qs = q ^ ((dloc >> 3) & 7);
                bf16x8 bb = *(const bf16x8*)&tile[dloc * 36 + qs * 4];
                acc[0][dd] = __builtin_amdgcn_mfma_f32_16x16x32_bf16(a0c[ks], bb, acc[0][dd], 0, 0, 0);
                acc[1][dd] = __builtin_amdgcn_mfma_f32_16x16x32_bf16(a1c[ks], bb, acc[1][dd], 0, 0, 0);
            }
        }
        __syncthreads();
        if (lc < 7) {
#pragma unroll
            for (int ks = 0; ks < 2; ++ks) { a0c[ks] = a0n[ks]; a1c[ks] = a1n[ks]; }
        }
    }
#undef XC_LOADG
#undef XC_LOADA
#pragma unroll
    for (int h = 0; h < 2; ++h)
#pragma unroll
        for (int dd = 0; dd < 2; ++dd)
#pragma unroll
            for (int r = 0; r < 4; ++r) {
                int c = 16 * h + lg * 4 + r;
                int d = dt * 128 + w * 32 + dd * 16 + l15;
                x_cb[((size_t)c * Bn + b) * Dn + d] = (short)f2bf(acc[h][dd][r]);
            }
}

// ---------------------------------------------------------------------------
extern "C" void kernel_launch(void* const* d_in, const int* in_sizes, int n_in,
                              void* d_out, int out_size, void* d_ws, size_t ws_size,
                              hipStream_t stream) {
    const float* in   = (const float*)d_in[0];
    const float* fc_w = (const float*)d_in[1];
    const float* fc_b = (const float*)d_in[2];
    float* out = (float*)d_out;

    char* p = (char*)d_ws;
    auto alloc = [&](size_t bytes) -> char* {
        char* r = p;
        p += (bytes + 255) & ~(size_t)255;
        return r;
    };
    short* in_bf  = (short*)alloc((size_t)Bn * Ln * Dn * 2);   // 64 MB
    short* fc_wT  = (short*)alloc((size_t)COn * Dn * 2);       // 4 MB
    short* fc_wb  = (short*)alloc((size_t)COn * Dn * 2);       // 4 MB
    short* w_vb   = (short*)alloc((size_t)Bn * Cn * Dn * 2);   // 4 MB
    short* c_wT   = (short*)alloc((size_t)Bn * Cn * Ln * 2);   // 2 MB
    short* x_cb   = (short*)alloc((size_t)Cn * Bn * Dn * 2);   // 4 MB
    short* v_bf   = (short*)alloc((size_t)Bn * Cn * On * 2);   // 256 KB
    float* rs_p   = (float*)alloc((size_t)Bn * 8 * Dn * 4);    // 2 MB
    unsigned short* rs_bf = (unsigned short*)alloc((size_t)Bn * Dn * 2);
    float* b_ij   = (float*)alloc((size_t)Bn * Ln * Cn * 4);   // 4 MB
    float* bias_v = (float*)alloc((size_t)Bn * Cn * 4);
    float* csum_p = (float*)alloc((size_t)8 * Bn * Cn * 4);

    k_ctr<<<dim3(32, Bn), 256, 0, stream>>>(in, in_bf, rs_p);
    k_prep2<<<384, 256, 0, stream>>>(fc_w, fc_wT, fc_wb, rs_p, rs_bf);
    k_sv3<<<dim3(4, Cn), 64, 0, stream>>>((const short*)rs_bf, csum_p, fc_wT,
                                          fc_b, v_bf, nullptr, bias_v, 1);
    for (int it = 1; it <= 2; ++it) {
        k_wv_m<<<dim3(4, Cn), 256, 0, stream>>>(fc_wb, v_bf, w_vb);
        k_route_m<<<dim3(8, Bn), 256, 0, stream>>>(in_bf, w_vb, bias_v, b_ij,
                                                   c_wT, csum_p,
                                                   (it == 1) ? 1 : 0,
                                                   (it == 2) ? 1 : 0);
        k_xc_m<<<dim3(8, Bn), 256, 0, stream>>>(in_bf, c_wT, x_cb);
        k_sv3<<<dim3(4, Cn), 64, 0, stream>>>(x_cb, csum_p, fc_wT, fc_b,
                                              v_bf, (it == 2) ? out : nullptr,
                                              bias_v, 0);
    }
}

// Round 12
// 180.868 us; speedup vs baseline: 1.4051x; 1.0522x over previous
//
#include <hip/hip_runtime.h>

// CapsuleLayer: B=64, L=512, D=1024, C=32, O=64, 3 routing iters.
// u_hat never materialized:
//   dots[b,l,c] = in[b,l,:]@w_v[b,c,:] + bias_v[b,c]   (w_v[b,c,d] = sum_o fc_w[d,cO+o] v[b,c,o])
//   s_j[b,c,:]  = x_c[b,c,:]@fc_w[:,c,:] + csum[b,c]*fc_b[c,:]   (x_c = sum_l c_w * in)
// All contractions via mfma_f32_16x16x32_bf16. Single bf16 input copy
// in_bf[b][l][d]. k_ctr: persistent 512-block form (4 d-slab loop).
// k_route2: K split across wave pairs (LDS-reduced) -> 4 waves/SIMD.
// k_xc_m: LDS l-pair transpose staging + T14 async-stage pipeline.

namespace {
constexpr int Bn = 64, Ln = 512, Dn = 1024, Cn = 32, On = 64, COn = Cn * On;
}

typedef float f32x4 __attribute__((ext_vector_type(4)));
typedef short bf16x8 __attribute__((ext_vector_type(8)));

static __device__ __forceinline__ unsigned f2bf(float f) {
    unsigned u = __float_as_uint(f);
    u += 0x7fff + ((u >> 16) & 1);   // RNE
    return u >> 16;
}

// ------------------------------------------------------------ conv ----------
// Persistent: grid (8 lc, 64 b); block loops 4 d-slabs of 256 (64l x 1024d
// total). Lane owns 8l x 8d micro-tile per slab. No LDS.
__global__ __launch_bounds__(256) void k_ctr(const float* __restrict__ in,
                                             short* __restrict__ in_bf,
                                             float* __restrict__ rs_p) {
    int lc = blockIdx.x, b = blockIdx.y;
    int l0 = lc * 64;
    int t = threadIdx.x, w = t >> 6, lane = t & 63;
    int db = lane & 7, lb = lane >> 3;
    int lloc = lb * 8;
#pragma unroll
    for (int ds = 0; ds < 4; ++ds) {
        int d0 = ds * 256;
        int dloc = w * 64 + db * 8;
        const float* src = in + ((size_t)b * Ln + l0 + lloc) * Dn + d0 + dloc;
        float4 ld[8][2];
#pragma unroll
        for (int r = 0; r < 8; ++r) {
            ld[r][0] = *(const float4*)(src + (size_t)r * Dn);
            ld[r][1] = *(const float4*)(src + (size_t)r * Dn + 4);
        }
        unsigned mr[8][4];
        float s[8];
#pragma unroll
        for (int k = 0; k < 8; ++k) s[k] = 0.f;
#pragma unroll
        for (int r = 0; r < 8; ++r) {
            const float* e = (const float*)&ld[r][0];
#pragma unroll
            for (int j = 0; j < 4; ++j)
                mr[r][j] = f2bf(e[2 * j]) | (f2bf(e[2 * j + 1]) << 16);
#pragma unroll
            for (int k = 0; k < 8; ++k) s[k] += e[k];
        }
        short* dbf = in_bf + ((size_t)b * Ln + l0 + lloc) * Dn + d0 + dloc;
#pragma unroll
        for (int r = 0; r < 8; ++r)
            *(uint4*)(dbf + (size_t)r * Dn) =
                make_uint4(mr[r][0], mr[r][1], mr[r][2], mr[r][3]);
#pragma unroll
        for (int k = 0; k < 8; ++k) {
            s[k] += __shfl_xor(s[k], 8, 64);
            s[k] += __shfl_xor(s[k], 16, 64);
            s[k] += __shfl_xor(s[k], 32, 64);
        }
        if (lb == 0) {
            float* rp = rs_p + ((size_t)b * 8 + lc) * Dn + d0 + dloc;
            *(float4*)rp = make_float4(s[0], s[1], s[2], s[3]);
            *(float4*)(rp + 4) = make_float4(s[4], s[5], s[6], s[7]);
        }
    }
}

// -------------------------------------------------------- wprep + rsred -----
// blocks [0,128): fc_w fp32 [d][co] -> fc_wT bf16 [co][d] + fc_wb bf16 [d][co]
// blocks [128,384): rsred — rs_p partials -> rs_bf (/32, bf16)
__global__ __launch_bounds__(256) void k_prep2(const float* __restrict__ fc_w,
                                               short* __restrict__ fc_wT,
                                               short* __restrict__ fc_wb,
                                               const float* __restrict__ rs_p,
                                               unsigned short* __restrict__ rs_bf) {
    __shared__ short tr[64 * 260];      // used by wprep blocks only
    int t = threadIdx.x;
    if (blockIdx.x < 128) {
        int id = blockIdx.x;
        int d0 = (id & 15) * 64;
        int co0 = (id >> 4) * 256;
        int grp = t >> 6, cq = t & 63;
#pragma unroll
        for (int i = 0; i < 16; ++i) {
            int row = grp + 4 * i;
            float4 x = *(const float4*)(fc_w + (size_t)(d0 + row) * COn + co0 + cq * 4);
            short4 s4 = make_short4((short)f2bf(x.x), (short)f2bf(x.y),
                                    (short)f2bf(x.z), (short)f2bf(x.w));
            *(short4*)(&tr[row * 260 + cq * 4]) = s4;
            *(short4*)(fc_wb + (size_t)(d0 + row) * COn + co0 + cq * 4) = s4;
        }
        __syncthreads();
#pragma unroll
        for (int i = 0; i < 8; ++i) {
            int idx = t + 256 * i;
            int corow = idx >> 3, slot = idx & 7;
            bf16x8 v;
#pragma unroll
            for (int j = 0; j < 8; ++j) v[j] = tr[(slot * 8 + j) * 260 + corow];
            *(bf16x8*)(fc_wT + (size_t)(co0 + corow) * Dn + d0 + slot * 8) = v;
        }
    } else {
        int id = blockIdx.x - 128;      // 0..255
        int b = id >> 2, dq = id & 3;
        int d = dq * 256 + t;
        float s = 0.f;
#pragma unroll
        for (int lc = 0; lc < 8; ++lc) s += rs_p[((size_t)b * 8 + lc) * Dn + d];
        rs_bf[b * Dn + d] = (unsigned short)f2bf(s * (1.0f / 32.0f));
    }
}

// ------------------------------------------------------- s -> squash -> v ---
// Per-(btile,c) MFMA GEMM: one wave computes S[16 b][64 o]. Grid (4, 32).
__global__ __launch_bounds__(64) void k_sv3(const short* __restrict__ xA,
                                            const float* __restrict__ csum_p,
                                            const short* __restrict__ fc_wT,
                                            const float* __restrict__ fc_b,
                                            short* __restrict__ v_bf,
                                            float* __restrict__ fout,
                                            float* __restrict__ bias_v,
                                            int mode0) {
    int w = blockIdx.x;                 // b-tile 0..3
    int c = blockIdx.y;
    int lane = threadIdx.x;             // 0..63
    int l15 = lane & 15, lg = lane >> 4;
    const short* A = mode0 ? xA : (xA + (size_t)c * Bn * Dn);   // [b][d]
    const short* Bw = fc_wT + (size_t)c * On * Dn;              // [o][d]
    f32x4 acc[4];
#pragma unroll
    for (int i = 0; i < 4; ++i) acc[i] = {0.f, 0.f, 0.f, 0.f};
#pragma unroll 4
    for (int ks = 0; ks < 32; ++ks) {
        int koff = ks * 32 + lg * 8;
        bf16x8 a = *(const bf16x8*)(A + (size_t)(w * 16 + l15) * Dn + koff);
#pragma unroll
        for (int dt = 0; dt < 4; ++dt) {
            bf16x8 bbf = *(const bf16x8*)(Bw + (size_t)(dt * 16 + l15) * Dn + koff);
            acc[dt] = __builtin_amdgcn_mfma_f32_16x16x32_bf16(a, bbf, acc[dt], 0, 0, 0);
        }
    }
    float fb[4];
#pragma unroll
    for (int dt = 0; dt < 4; ++dt) fb[dt] = fc_b[c * On + dt * 16 + l15];
#pragma unroll
    for (int r = 0; r < 4; ++r) {
        int brow = w * 16 + lg * 4 + r;
        float cs;
        if (mode0) {
            cs = 16.0f;
        } else {
            cs = 0.f;
#pragma unroll
            for (int lt = 0; lt < 16; ++lt) cs += csum_p[((size_t)lt * Bn + brow) * Cn + c];
        }
        float s0 = acc[0][r] + cs * fb[0];
        float s1 = acc[1][r] + cs * fb[1];
        float s2 = acc[2][r] + cs * fb[2];
        float s3 = acc[3][r] + cs * fb[3];
        float sq = s0 * s0 + s1 * s1 + s2 * s2 + s3 * s3;
        sq += __shfl_xor(sq, 1, 64); sq += __shfl_xor(sq, 2, 64);
        sq += __shfl_xor(sq, 4, 64); sq += __shfl_xor(sq, 8, 64);
        float scale = sq / (1.0f + sq) * rsqrtf(sq + 1e-8f);
        float v0 = scale * s0, v1 = scale * s1, v2 = scale * s2, v3 = scale * s3;
        size_t vo = ((size_t)brow * Cn + c) * On;
        v_bf[vo + 0 * 16 + l15] = (short)f2bf(v0);
        v_bf[vo + 1 * 16 + l15] = (short)f2bf(v1);
        v_bf[vo + 2 * 16 + l15] = (short)f2bf(v2);
        v_bf[vo + 3 * 16 + l15] = (short)f2bf(v3);
        if (fout) {
            fout[vo + 0 * 16 + l15] = v0;
            fout[vo + 1 * 16 + l15] = v1;
            fout[vo + 2 * 16 + l15] = v2;
            fout[vo + 3 * 16 + l15] = v3;
        }
        float bv = fb[0] * v0 + fb[1] * v1 + fb[2] * v2 + fb[3] * v3;
        bv += __shfl_xor(bv, 1, 64); bv += __shfl_xor(bv, 2, 64);
        bv += __shfl_xor(bv, 4, 64); bv += __shfl_xor(bv, 8, 64);
        if (l15 == 0) bias_v[brow * Cn + c] = bv;
    }
}

// ------------------------------------------- w_v via MFMA (contract o=64) ---
// grid (4 dslab, 32 c), 256 thr / 4 waves; wave: 64 d x 64 b, K=64.
__global__ __launch_bounds__(256) void k_wv_m(const short* __restrict__ fc_wb,
                                              const short* __restrict__ v_bf,
                                              short* __restrict__ w_vb) {
    int dsl = blockIdx.x, c = blockIdx.y;
    int t = threadIdx.x, w = t >> 6, lane = t & 63;
    int l15 = lane & 15, lg = lane >> 4;
    int dbase = dsl * 256 + w * 64;
    f32x4 acc[4][4];
#pragma unroll
    for (int i = 0; i < 4; ++i)
#pragma unroll
        for (int j = 0; j < 4; ++j) acc[i][j] = {0.f, 0.f, 0.f, 0.f};
#pragma unroll
    for (int ks = 0; ks < 2; ++ks) {
        int o = ks * 32 + lg * 8;
        bf16x8 bfr[4];
#pragma unroll
        for (int nt = 0; nt < 4; ++nt)
            bfr[nt] = *(const bf16x8*)(v_bf + ((size_t)(nt * 16 + l15) * Cn + c) * On + o);
#pragma unroll
        for (int mt = 0; mt < 4; ++mt) {
            bf16x8 a = *(const bf16x8*)(fc_wb + (size_t)(dbase + mt * 16 + l15) * COn + c * On + o);
#pragma unroll
            for (int nt = 0; nt < 4; ++nt)
                acc[mt][nt] = __builtin_amdgcn_mfma_f32_16x16x32_bf16(a, bfr[nt], acc[mt][nt], 0, 0, 0);
        }
    }
#pragma unroll
    for (int mt = 0; mt < 4; ++mt)
#pragma unroll
        for (int nt = 0; nt < 4; ++nt) {
            int bb = nt * 16 + l15;
            int d = dbase + mt * 16 + lg * 4;
            *(short4*)(w_vb + ((size_t)bb * Cn + c) * Dn + d) =
                make_short4((short)f2bf(acc[mt][nt][0]), (short)f2bf(acc[mt][nt][1]),
                            (short)f2bf(acc[mt][nt][2]), (short)f2bf(acc[mt][nt][3]));
        }
}

// ------------------------------- dots -> b_ij update -> softmax -> c_wT -----
// K-split: grid (16 lt2, 64 b), 4 waves = 2 l-groups x 2 K-halves. Each wave
// does K=512; partners LDS-reduce (conflict-free b32 lanes). 1024 blocks ->
// 4 waves/SIMD (2x the unsplit form). Epilogue on kh==0 waves.
__global__ __launch_bounds__(256) void k_route2(const short* __restrict__ in_bf,
                                                const short* __restrict__ w_v,
                                                const float* __restrict__ bias_v,
                                                float* __restrict__ b_ij,
                                                short* __restrict__ c_wT,
                                                float* __restrict__ csum_p,
                                                int first, int last) {
    __shared__ float red[2][8][64];     // [lgrp][acc j][lane]
    __shared__ short cw_sh[Cn * 40];    // [c][32 l + pad]
    __shared__ float cs_sh[2][Cn];
    int lt2 = blockIdx.x, b = blockIdx.y;
    int t = threadIdx.x, w = t >> 6, lane = t & 63;
    int lgrp = w >> 1, kh = w & 1;
    int l15 = lane & 15, lg = lane >> 4;
    int l0 = lt2 * 32 + lgrp * 16;
    f32x4 acc0 = {0.f, 0.f, 0.f, 0.f}, acc1 = {0.f, 0.f, 0.f, 0.f};
    const short* Ap = in_bf + ((size_t)b * Ln + l0 + l15) * Dn + kh * 512;
    const short* Bp = w_v + (size_t)b * Cn * Dn + kh * 512;
#pragma unroll 4
    for (int ks = 0; ks < 16; ++ks) {
        int koff = ks * 32 + lg * 8;
        bf16x8 a = *(const bf16x8*)(Ap + koff);
        bf16x8 b0 = *(const bf16x8*)(Bp + (size_t)l15 * Dn + koff);
        bf16x8 b1 = *(const bf16x8*)(Bp + (size_t)(l15 + 16) * Dn + koff);
        acc0 = __builtin_amdgcn_mfma_f32_16x16x32_bf16(a, b0, acc0, 0, 0, 0);
        acc1 = __builtin_amdgcn_mfma_f32_16x16x32_bf16(a, b1, acc1, 0, 0, 0);
    }
    if (kh == 1) {
#pragma unroll
        for (int j = 0; j < 4; ++j) {
            red[lgrp][j][lane] = acc0[j];
            red[lgrp][4 + j][lane] = acc1[j];
        }
    }
    __syncthreads();
    if (kh == 0) {
#pragma unroll
        for (int j = 0; j < 4; ++j) {
            acc0[j] += red[lgrp][j][lane];
            acc1[j] += red[lgrp][4 + j][lane];
        }
        float bv0 = bias_v[b * Cn + l15];
        float bv1 = bias_v[b * Cn + l15 + 16];
        float csa0 = 0.f, csa1 = 0.f;
#pragma unroll
        for (int r = 0; r < 4; ++r) {
            int lrow = l0 + lg * 4 + r;
            size_t boff = ((size_t)b * Ln + lrow) * Cn;
            float d0 = acc0[r] + bv0, d1 = acc1[r] + bv1;
            if (!first) { d0 += b_ij[boff + l15]; d1 += b_ij[boff + l15 + 16]; }
            if (!last) {
                b_ij[boff + l15] = d0;
                b_ij[boff + l15 + 16] = d1;
            }
            float m = fmaxf(d0, d1);
            m = fmaxf(m, __shfl_xor(m, 1, 64)); m = fmaxf(m, __shfl_xor(m, 2, 64));
            m = fmaxf(m, __shfl_xor(m, 4, 64)); m = fmaxf(m, __shfl_xor(m, 8, 64));
            float e0 = __expf(d0 - m), e1 = __expf(d1 - m);
            float sm = e0 + e1;
            sm += __shfl_xor(sm, 1, 64); sm += __shfl_xor(sm, 2, 64);
            sm += __shfl_xor(sm, 4, 64); sm += __shfl_xor(sm, 8, 64);
            float inv = 1.0f / sm;
            float cw0 = e0 * inv, cw1 = e1 * inv;
            csa0 += cw0; csa1 += cw1;
            int ll = lgrp * 16 + lg * 4 + r;
            cw_sh[l15 * 40 + ll] = (short)f2bf(cw0);
            cw_sh[(l15 + 16) * 40 + ll] = (short)f2bf(cw1);
        }
        csa0 += __shfl_xor(csa0, 16, 64); csa0 += __shfl_xor(csa0, 32, 64);
        csa1 += __shfl_xor(csa1, 16, 64); csa1 += __shfl_xor(csa1, 32, 64);
        if (lg == 0) { cs_sh[lgrp][l15] = csa0; cs_sh[lgrp][l15 + 16] = csa1; }
    }
    __syncthreads();
    if (t < Cn) {
        float s = cs_sh[0][t] + cs_sh[1][t];
        csum_p[((size_t)lt2 * Bn + b) * Cn + t] = s;
    }
    if (t < 128) {
        int cc = t >> 2, slot = t & 3;
        bf16x8 vv;
#pragma unroll
        for (int j = 0; j < 8; ++j) vv[j] = cw_sh[cc * 40 + slot * 8 + j];
        *(bf16x8*)(c_wT + ((size_t)b * Cn + cc) * Ln + lt2 * 32 + slot * 8) = vv;
    }
}

// ----------------------------------------- x_cb[c][b][d] = c_w^T @ in -------
// grid (8 dt, 64 b), 256 thr / 4 waves. T14 async-stage pipeline; LDS
// [128 d][36 u32] l-pair pack, XOR-chunk swizzle.
__global__ __launch_bounds__(256) void k_xc_m(const short* __restrict__ in_bf,
                                              const short* __restrict__ c_wT,
                                              short* __restrict__ x_cb) {
    __shared__ unsigned tile[128 * 36];   // 18432 B
    int dt = blockIdx.x, b = blockIdx.y;
    int t = threadIdx.x, w = t >> 6, lane = t & 63;
    int l15 = lane & 15, lg = lane >> 4;
    f32x4 acc[2][2];
#pragma unroll
    for (int h = 0; h < 2; ++h)
#pragma unroll
        for (int dd = 0; dd < 2; ++dd) acc[h][dd] = {0.f, 0.f, 0.f, 0.f};
    const short* A = c_wT + (size_t)b * Cn * Ln;   // [c][l]

    int oct = t & 15, lpA = t >> 4, lpB = lpA + 16;
    const short* gbase = in_bf + (size_t)b * Ln * Dn + dt * 128 + oct * 8;
    int colA = lpA ^ ((oct & 7) << 2);
    int colB = lpB ^ ((oct & 7) << 2);
    unsigned* trow = &tile[(oct * 8) * 36];

    bf16x8 ra0, ra1, rb0, rb1;
    bf16x8 a0c[2], a1c[2], a0n[2], a1n[2];

#define XC_LOADG(LC)                                                          \
    {                                                                         \
        const short* sA = gbase + (size_t)((LC) * 64 + 2 * lpA) * Dn;         \
        const short* sB = gbase + (size_t)((LC) * 64 + 2 * lpB) * Dn;         \
        ra0 = *(const bf16x8*)sA; ra1 = *(const bf16x8*)(sA + Dn);            \
        rb0 = *(const bf16x8*)sB; rb1 = *(const bf16x8*)(sB + Dn);            \
    }
#define XC_LOADA(LC, D0, D1)                                                  \
    _Pragma("unroll")                                                         \
    for (int ks = 0; ks < 2; ++ks) {                                          \
        int off = (LC) * 64 + ks * 32 + lg * 8;                               \
        D0[ks] = *(const bf16x8*)(A + (size_t)l15 * Ln + off);                \
        D1[ks] = *(const bf16x8*)(A + (size_t)(l15 + 16) * Ln + off);         \
    }

    XC_LOADG(0);
    XC_LOADA(0, a0c, a1c);

    for (int lc = 0; lc < 8; ++lc) {
#pragma unroll
        for (int k = 0; k < 8; ++k) {
            trow[k * 36 + colA] = (unsigned)(unsigned short)ra0[k] |
                                  ((unsigned)(unsigned short)ra1[k] << 16);
            trow[k * 36 + colB] = (unsigned)(unsigned short)rb0[k] |
                                  ((unsigned)(unsigned short)rb1[k] << 16);
        }
        __syncthreads();
        if (lc < 7) {
            XC_LOADG(lc + 1);
            XC_LOADA(lc + 1, a0n, a1n);
        }
#pragma unroll
        for (int ks = 0; ks < 2; ++ks) {
            int q = ks * 4 + lg;
#pragma unroll
            for (int dd = 0; dd < 2; ++dd) {
                int dloc = w * 32 + dd * 16 + l15;
                int qs = q ^ ((dloc >> 3) & 7);
                bf16x8 bb = *(const bf16x8*)&tile[dloc * 36 + qs * 4];
                acc[0][dd] = __builtin_amdgcn_mfma_f32_16x16x32_bf16(a0c[ks], bb, acc[0][dd], 0, 0, 0);
                acc[1][dd] = __builtin_amdgcn_mfma_f32_16x16x32_bf16(a1c[ks], bb, acc[1][dd], 0, 0, 0);
            }
        }
        __syncthreads();
        if (lc < 7) {
#pragma unroll
            for (int ks = 0; ks < 2; ++ks) { a0c[ks] = a0n[ks]; a1c[ks] = a1n[ks]; }
        }
    }
#undef XC_LOADG
#undef XC_LOADA
#pragma unroll
    for (int h = 0; h < 2; ++h)
#pragma unroll
        for (int dd = 0; dd < 2; ++dd)
#pragma unroll
            for (int r = 0; r < 4; ++r) {
                int c = 16 * h + lg * 4 + r;
                int d = dt * 128 + w * 32 + dd * 16 + l15;
                x_cb[((size_t)c * Bn + b) * Dn + d] = (short)f2bf(acc[h][dd][r]);
            }
}

// ---------------------------------------------------------------------------
extern "C" void kernel_launch(void* const* d_in, const int* in_sizes, int n_in,
                              void* d_out, int out_size, void* d_ws, size_t ws_size,
                              hipStream_t stream) {
    const float* in   = (const float*)d_in[0];
    const float* fc_w = (const float*)d_in[1];
    const float* fc_b = (const float*)d_in[2];
    float* out = (float*)d_out;

    char* p = (char*)d_ws;
    auto alloc = [&](size_t bytes) -> char* {
        char* r = p;
        p += (bytes + 255) & ~(size_t)255;
        return r;
    };
    short* in_bf  = (short*)alloc((size_t)Bn * Ln * Dn * 2);   // 64 MB
    short* fc_wT  = (short*)alloc((size_t)COn * Dn * 2);       // 4 MB
    short* fc_wb  = (short*)alloc((size_t)COn * Dn * 2);       // 4 MB
    short* w_vb   = (short*)alloc((size_t)Bn * Cn * Dn * 2);   // 4 MB
    short* c_wT   = (short*)alloc((size_t)Bn * Cn * Ln * 2);   // 2 MB
    short* x_cb   = (short*)alloc((size_t)Cn * Bn * Dn * 2);   // 4 MB
    short* v_bf   = (short*)alloc((size_t)Bn * Cn * On * 2);   // 256 KB
    float* rs_p   = (float*)alloc((size_t)Bn * 8 * Dn * 4);    // 2 MB
    unsigned short* rs_bf = (unsigned short*)alloc((size_t)Bn * Dn * 2);
    float* b_ij   = (float*)alloc((size_t)Bn * Ln * Cn * 4);   // 4 MB
    float* bias_v = (float*)alloc((size_t)Bn * Cn * 4);
    float* csum_p = (float*)alloc((size_t)16 * Bn * Cn * 4);

    k_ctr<<<dim3(8, Bn), 256, 0, stream>>>(in, in_bf, rs_p);
    k_prep2<<<384, 256, 0, stream>>>(fc_w, fc_wT, fc_wb, rs_p, rs_bf);
    k_sv3<<<dim3(4, Cn), 64, 0, stream>>>((const short*)rs_bf, csum_p, fc_wT,
                                          fc_b, v_bf, nullptr, bias_v, 1);
    for (int it = 1; it <= 2; ++it) {
        k_wv_m<<<dim3(4, Cn), 256, 0, stream>>>(fc_wb, v_bf, w_vb);
        k_route2<<<dim3(16, Bn), 256, 0, stream>>>(in_bf, w_vb, bias_v, b_ij,
                                                   c_wT, csum_p,
                                                   (it == 1) ? 1 : 0,
                                                   (it == 2) ? 1 : 0);
        k_xc_m<<<dim3(8, Bn), 256, 0, stream>>>(in_bf, c_wT, x_cb);
        k_sv3<<<dim3(4, Cn), 64, 0, stream>>>(x_cb, csum_p, fc_wT, fc_b,
                                              v_bf, (it == 2) ? out : nullptr,
                                              bias_v, 0);
    }
}

// Round 13
// 172.983 us; speedup vs baseline: 1.4692x; 1.0456x over previous
//
#include <hip/hip_runtime.h>

// CapsuleLayer: B=64, L=512, D=1024, C=32, O=64, 3 routing iters.
// u_hat never materialized:
//   dots[b,l,c] = in[b,l,:]@w_v[b,c,:] + bias_v[b,c]   (w_v[b,c,d] = sum_o fc_w[d,cO+o] v[b,c,o])
//   s_j[b,c,:]  = x_c[b,c,:]@fc_w[:,c,:] + csum[b,c]*fc_b[c,:]   (x_c = sum_l c_w * in)
// All contractions via mfma_f32_16x16x32_bf16. Single bf16 input copy
// in_bf[b][l][d]. k_ctr: fully-sequential streaming form — wave w owns
// d-quarter, block walks 32 complete rows contiguously (1 KB/load instr);
// rowsum = per-lane register accumulation, 16 partials.
// k_route2: K split across wave pairs (LDS-reduced) -> 4 waves/SIMD.
// k_xc_m: LDS l-pair transpose staging + T14 async-stage pipeline.

namespace {
constexpr int Bn = 64, Ln = 512, Dn = 1024, Cn = 32, On = 64, COn = Cn * On;
}

typedef float f32x4 __attribute__((ext_vector_type(4)));
typedef short bf16x8 __attribute__((ext_vector_type(8)));

static __device__ __forceinline__ unsigned f2bf(float f) {
    unsigned u = __float_as_uint(f);
    u += 0x7fff + ((u >> 16) & 1);   // RNE
    return u >> 16;
}

// ------------------------------------------------------------ conv ----------
// grid (16 lc, 64 b): block streams 32 complete rows (128 KB contiguous).
// Wave w covers d in [w*256, w*256+256); lane owns one float4 column.
// Per row: 4 waves jointly read the full 4 KB row; packed bf16 store 512 B
// contiguous per wave. Rowsum: per-lane f32x4 accumulator, no cross-lane.
__global__ __launch_bounds__(256) void k_ctr(const float* __restrict__ in,
                                             short* __restrict__ in_bf,
                                             float* __restrict__ rs_p) {
    int lc = blockIdx.x, b = blockIdx.y;
    int t = threadIdx.x, w = t >> 6, lane = t & 63;
    int l0 = lc * 32;
    int d0 = w * 256 + lane * 4;
    const float* src = in + ((size_t)b * Ln + l0) * Dn + d0;
    short* dst = in_bf + ((size_t)b * Ln + l0) * Dn + d0;
    float4 s4 = make_float4(0.f, 0.f, 0.f, 0.f);
#pragma unroll 8
    for (int r = 0; r < 32; ++r) {
        float4 x = *(const float4*)(src + (size_t)r * Dn);
        s4.x += x.x; s4.y += x.y; s4.z += x.z; s4.w += x.w;
        unsigned lo = f2bf(x.x) | (f2bf(x.y) << 16);
        unsigned hi = f2bf(x.z) | (f2bf(x.w) << 16);
        *(uint2*)(dst + (size_t)r * Dn) = make_uint2(lo, hi);
    }
    *(float4*)(rs_p + ((size_t)b * 16 + lc) * Dn + d0) = s4;
}

// -------------------------------------------------------- wprep + rsred -----
// blocks [0,128): fc_w fp32 [d][co] -> fc_wT bf16 [co][d] + fc_wb bf16 [d][co]
// blocks [128,384): rsred — rs_p partials (16) -> rs_bf (/32, bf16)
__global__ __launch_bounds__(256) void k_prep2(const float* __restrict__ fc_w,
                                               short* __restrict__ fc_wT,
                                               short* __restrict__ fc_wb,
                                               const float* __restrict__ rs_p,
                                               unsigned short* __restrict__ rs_bf) {
    __shared__ short tr[64 * 260];      // used by wprep blocks only
    int t = threadIdx.x;
    if (blockIdx.x < 128) {
        int id = blockIdx.x;
        int d0 = (id & 15) * 64;
        int co0 = (id >> 4) * 256;
        int grp = t >> 6, cq = t & 63;
#pragma unroll
        for (int i = 0; i < 16; ++i) {
            int row = grp + 4 * i;
            float4 x = *(const float4*)(fc_w + (size_t)(d0 + row) * COn + co0 + cq * 4);
            short4 s4 = make_short4((short)f2bf(x.x), (short)f2bf(x.y),
                                    (short)f2bf(x.z), (short)f2bf(x.w));
            *(short4*)(&tr[row * 260 + cq * 4]) = s4;
            *(short4*)(fc_wb + (size_t)(d0 + row) * COn + co0 + cq * 4) = s4;
        }
        __syncthreads();
#pragma unroll
        for (int i = 0; i < 8; ++i) {
            int idx = t + 256 * i;
            int corow = idx >> 3, slot = idx & 7;
            bf16x8 v;
#pragma unroll
            for (int j = 0; j < 8; ++j) v[j] = tr[(slot * 8 + j) * 260 + corow];
            *(bf16x8*)(fc_wT + (size_t)(co0 + corow) * Dn + d0 + slot * 8) = v;
        }
    } else {
        int id = blockIdx.x - 128;      // 0..255
        int b = id >> 2, dq = id & 3;
        int d = dq * 256 + t;
        float s = 0.f;
#pragma unroll
        for (int lc = 0; lc < 16; ++lc) s += rs_p[((size_t)b * 16 + lc) * Dn + d];
        rs_bf[b * Dn + d] = (unsigned short)f2bf(s * (1.0f / 32.0f));
    }
}

// ------------------------------------------------------- s -> squash -> v ---
// Per-(btile,c) MFMA GEMM: one wave computes S[16 b][64 o]. Grid (4, 32).
__global__ __launch_bounds__(64) void k_sv3(const short* __restrict__ xA,
                                            const float* __restrict__ csum_p,
                                            const short* __restrict__ fc_wT,
                                            const float* __restrict__ fc_b,
                                            short* __restrict__ v_bf,
                                            float* __restrict__ fout,
                                            float* __restrict__ bias_v,
                                            int mode0) {
    int w = blockIdx.x;                 // b-tile 0..3
    int c = blockIdx.y;
    int lane = threadIdx.x;             // 0..63
    int l15 = lane & 15, lg = lane >> 4;
    const short* A = mode0 ? xA : (xA + (size_t)c * Bn * Dn);   // [b][d]
    const short* Bw = fc_wT + (size_t)c * On * Dn;              // [o][d]
    f32x4 acc[4];
#pragma unroll
    for (int i = 0; i < 4; ++i) acc[i] = {0.f, 0.f, 0.f, 0.f};
#pragma unroll 4
    for (int ks = 0; ks < 32; ++ks) {
        int koff = ks * 32 + lg * 8;
        bf16x8 a = *(const bf16x8*)(A + (size_t)(w * 16 + l15) * Dn + koff);
#pragma unroll
        for (int dt = 0; dt < 4; ++dt) {
            bf16x8 bbf = *(const bf16x8*)(Bw + (size_t)(dt * 16 + l15) * Dn + koff);
            acc[dt] = __builtin_amdgcn_mfma_f32_16x16x32_bf16(a, bbf, acc[dt], 0, 0, 0);
        }
    }
    float fb[4];
#pragma unroll
    for (int dt = 0; dt < 4; ++dt) fb[dt] = fc_b[c * On + dt * 16 + l15];
#pragma unroll
    for (int r = 0; r < 4; ++r) {
        int brow = w * 16 + lg * 4 + r;
        float cs;
        if (mode0) {
            cs = 16.0f;
        } else {
            cs = 0.f;
#pragma unroll
            for (int lt = 0; lt < 16; ++lt) cs += csum_p[((size_t)lt * Bn + brow) * Cn + c];
        }
        float s0 = acc[0][r] + cs * fb[0];
        float s1 = acc[1][r] + cs * fb[1];
        float s2 = acc[2][r] + cs * fb[2];
        float s3 = acc[3][r] + cs * fb[3];
        float sq = s0 * s0 + s1 * s1 + s2 * s2 + s3 * s3;
        sq += __shfl_xor(sq, 1, 64); sq += __shfl_xor(sq, 2, 64);
        sq += __shfl_xor(sq, 4, 64); sq += __shfl_xor(sq, 8, 64);
        float scale = sq / (1.0f + sq) * rsqrtf(sq + 1e-8f);
        float v0 = scale * s0, v1 = scale * s1, v2 = scale * s2, v3 = scale * s3;
        size_t vo = ((size_t)brow * Cn + c) * On;
        v_bf[vo + 0 * 16 + l15] = (short)f2bf(v0);
        v_bf[vo + 1 * 16 + l15] = (short)f2bf(v1);
        v_bf[vo + 2 * 16 + l15] = (short)f2bf(v2);
        v_bf[vo + 3 * 16 + l15] = (short)f2bf(v3);
        if (fout) {
            fout[vo + 0 * 16 + l15] = v0;
            fout[vo + 1 * 16 + l15] = v1;
            fout[vo + 2 * 16 + l15] = v2;
            fout[vo + 3 * 16 + l15] = v3;
        }
        float bv = fb[0] * v0 + fb[1] * v1 + fb[2] * v2 + fb[3] * v3;
        bv += __shfl_xor(bv, 1, 64); bv += __shfl_xor(bv, 2, 64);
        bv += __shfl_xor(bv, 4, 64); bv += __shfl_xor(bv, 8, 64);
        if (l15 == 0) bias_v[brow * Cn + c] = bv;
    }
}

// ------------------------------------------- w_v via MFMA (contract o=64) ---
// grid (4 dslab, 32 c), 256 thr / 4 waves; wave: 64 d x 64 b, K=64.
__global__ __launch_bounds__(256) void k_wv_m(const short* __restrict__ fc_wb,
                                              const short* __restrict__ v_bf,
                                              short* __restrict__ w_vb) {
    int dsl = blockIdx.x, c = blockIdx.y;
    int t = threadIdx.x, w = t >> 6, lane = t & 63;
    int l15 = lane & 15, lg = lane >> 4;
    int dbase = dsl * 256 + w * 64;
    f32x4 acc[4][4];
#pragma unroll
    for (int i = 0; i < 4; ++i)
#pragma unroll
        for (int j = 0; j < 4; ++j) acc[i][j] = {0.f, 0.f, 0.f, 0.f};
#pragma unroll
    for (int ks = 0; ks < 2; ++ks) {
        int o = ks * 32 + lg * 8;
        bf16x8 bfr[4];
#pragma unroll
        for (int nt = 0; nt < 4; ++nt)
            bfr[nt] = *(const bf16x8*)(v_bf + ((size_t)(nt * 16 + l15) * Cn + c) * On + o);
#pragma unroll
        for (int mt = 0; mt < 4; ++mt) {
            bf16x8 a = *(const bf16x8*)(fc_wb + (size_t)(dbase + mt * 16 + l15) * COn + c * On + o);
#pragma unroll
            for (int nt = 0; nt < 4; ++nt)
                acc[mt][nt] = __builtin_amdgcn_mfma_f32_16x16x32_bf16(a, bfr[nt], acc[mt][nt], 0, 0, 0);
        }
    }
#pragma unroll
    for (int mt = 0; mt < 4; ++mt)
#pragma unroll
        for (int nt = 0; nt < 4; ++nt) {
            int bb = nt * 16 + l15;
            int d = dbase + mt * 16 + lg * 4;
            *(short4*)(w_vb + ((size_t)bb * Cn + c) * Dn + d) =
                make_short4((short)f2bf(acc[mt][nt][0]), (short)f2bf(acc[mt][nt][1]),
                            (short)f2bf(acc[mt][nt][2]), (short)f2bf(acc[mt][nt][3]));
        }
}

// ------------------------------- dots -> b_ij update -> softmax -> c_wT -----
// K-split: grid (16 lt2, 64 b), 4 waves = 2 l-groups x 2 K-halves. Each wave
// does K=512; partners LDS-reduce (conflict-free b32 lanes). 1024 blocks ->
// 4 waves/SIMD. Epilogue on kh==0 waves.
__global__ __launch_bounds__(256) void k_route2(const short* __restrict__ in_bf,
                                                const short* __restrict__ w_v,
                                                const float* __restrict__ bias_v,
                                                float* __restrict__ b_ij,
                                                short* __restrict__ c_wT,
                                                float* __restrict__ csum_p,
                                                int first, int last) {
    __shared__ float red[2][8][64];     // [lgrp][acc j][lane]
    __shared__ short cw_sh[Cn * 40];    // [c][32 l + pad]
    __shared__ float cs_sh[2][Cn];
    int lt2 = blockIdx.x, b = blockIdx.y;
    int t = threadIdx.x, w = t >> 6, lane = t & 63;
    int lgrp = w >> 1, kh = w & 1;
    int l15 = lane & 15, lg = lane >> 4;
    int l0 = lt2 * 32 + lgrp * 16;
    f32x4 acc0 = {0.f, 0.f, 0.f, 0.f}, acc1 = {0.f, 0.f, 0.f, 0.f};
    const short* Ap = in_bf + ((size_t)b * Ln + l0 + l15) * Dn + kh * 512;
    const short* Bp = w_v + (size_t)b * Cn * Dn + kh * 512;
#pragma unroll 4
    for (int ks = 0; ks < 16; ++ks) {
        int koff = ks * 32 + lg * 8;
        bf16x8 a = *(const bf16x8*)(Ap + koff);
        bf16x8 b0 = *(const bf16x8*)(Bp + (size_t)l15 * Dn + koff);
        bf16x8 b1 = *(const bf16x8*)(Bp + (size_t)(l15 + 16) * Dn + koff);
        acc0 = __builtin_amdgcn_mfma_f32_16x16x32_bf16(a, b0, acc0, 0, 0, 0);
        acc1 = __builtin_amdgcn_mfma_f32_16x16x32_bf16(a, b1, acc1, 0, 0, 0);
    }
    if (kh == 1) {
#pragma unroll
        for (int j = 0; j < 4; ++j) {
            red[lgrp][j][lane] = acc0[j];
            red[lgrp][4 + j][lane] = acc1[j];
        }
    }
    __syncthreads();
    if (kh == 0) {
#pragma unroll
        for (int j = 0; j < 4; ++j) {
            acc0[j] += red[lgrp][j][lane];
            acc1[j] += red[lgrp][4 + j][lane];
        }
        float bv0 = bias_v[b * Cn + l15];
        float bv1 = bias_v[b * Cn + l15 + 16];
        float csa0 = 0.f, csa1 = 0.f;
#pragma unroll
        for (int r = 0; r < 4; ++r) {
            int lrow = l0 + lg * 4 + r;
            size_t boff = ((size_t)b * Ln + lrow) * Cn;
            float d0 = acc0[r] + bv0, d1 = acc1[r] + bv1;
            if (!first) { d0 += b_ij[boff + l15]; d1 += b_ij[boff + l15 + 16]; }
            if (!last) {
                b_ij[boff + l15] = d0;
                b_ij[boff + l15 + 16] = d1;
            }
            float m = fmaxf(d0, d1);
            m = fmaxf(m, __shfl_xor(m, 1, 64)); m = fmaxf(m, __shfl_xor(m, 2, 64));
            m = fmaxf(m, __shfl_xor(m, 4, 64)); m = fmaxf(m, __shfl_xor(m, 8, 64));
            float e0 = __expf(d0 - m), e1 = __expf(d1 - m);
            float sm = e0 + e1;
            sm += __shfl_xor(sm, 1, 64); sm += __shfl_xor(sm, 2, 64);
            sm += __shfl_xor(sm, 4, 64); sm += __shfl_xor(sm, 8, 64);
            float inv = 1.0f / sm;
            float cw0 = e0 * inv, cw1 = e1 * inv;
            csa0 += cw0; csa1 += cw1;
            int ll = lgrp * 16 + lg * 4 + r;
            cw_sh[l15 * 40 + ll] = (short)f2bf(cw0);
            cw_sh[(l15 + 16) * 40 + ll] = (short)f2bf(cw1);
        }
        csa0 += __shfl_xor(csa0, 16, 64); csa0 += __shfl_xor(csa0, 32, 64);
        csa1 += __shfl_xor(csa1, 16, 64); csa1 += __shfl_xor(csa1, 32, 64);
        if (lg == 0) { cs_sh[lgrp][l15] = csa0; cs_sh[lgrp][l15 + 16] = csa1; }
    }
    __syncthreads();
    if (t < Cn) {
        float s = cs_sh[0][t] + cs_sh[1][t];
        csum_p[((size_t)lt2 * Bn + b) * Cn + t] = s;
    }
    if (t < 128) {
        int cc = t >> 2, slot = t & 3;
        bf16x8 vv;
#pragma unroll
        for (int j = 0; j < 8; ++j) vv[j] = cw_sh[cc * 40 + slot * 8 + j];
        *(bf16x8*)(c_wT + ((size_t)b * Cn + cc) * Ln + lt2 * 32 + slot * 8) = vv;
    }
}

// ----------------------------------------- x_cb[c][b][d] = c_w^T @ in -------
// grid (8 dt, 64 b), 256 thr / 4 waves. T14 async-stage pipeline; LDS
// [128 d][36 u32] l-pair pack, XOR-chunk swizzle.
__global__ __launch_bounds__(256) void k_xc_m(const short* __restrict__ in_bf,
                                              const short* __restrict__ c_wT,
                                              short* __restrict__ x_cb) {
    __shared__ unsigned tile[128 * 36];   // 18432 B
    int dt = blockIdx.x, b = blockIdx.y;
    int t = threadIdx.x, w = t >> 6, lane = t & 63;
    int l15 = lane & 15, lg = lane >> 4;
    f32x4 acc[2][2];
#pragma unroll
    for (int h = 0; h < 2; ++h)
#pragma unroll
        for (int dd = 0; dd < 2; ++dd) acc[h][dd] = {0.f, 0.f, 0.f, 0.f};
    const short* A = c_wT + (size_t)b * Cn * Ln;   // [c][l]

    int oct = t & 15, lpA = t >> 4, lpB = lpA + 16;
    const short* gbase = in_bf + (size_t)b * Ln * Dn + dt * 128 + oct * 8;
    int colA = lpA ^ ((oct & 7) << 2);
    int colB = lpB ^ ((oct & 7) << 2);
    unsigned* trow = &tile[(oct * 8) * 36];

    bf16x8 ra0, ra1, rb0, rb1;
    bf16x8 a0c[2], a1c[2], a0n[2], a1n[2];

#define XC_LOADG(LC)                                                          \
    {                                                                         \
        const short* sA = gbase + (size_t)((LC) * 64 + 2 * lpA) * Dn;         \
        const short* sB = gbase + (size_t)((LC) * 64 + 2 * lpB) * Dn;         \
        ra0 = *(const bf16x8*)sA; ra1 = *(const bf16x8*)(sA + Dn);            \
        rb0 = *(const bf16x8*)sB; rb1 = *(const bf16x8*)(sB + Dn);            \
    }
#define XC_LOADA(LC, D0, D1)                                                  \
    _Pragma("unroll")                                                         \
    for (int ks = 0; ks < 2; ++ks) {                                          \
        int off = (LC) * 64 + ks * 32 + lg * 8;                               \
        D0[ks] = *(const bf16x8*)(A + (size_t)l15 * Ln + off);                \
        D1[ks] = *(const bf16x8*)(A + (size_t)(l15 + 16) * Ln + off);         \
    }

    XC_LOADG(0);
    XC_LOADA(0, a0c, a1c);

    for (int lc = 0; lc < 8; ++lc) {
#pragma unroll
        for (int k = 0; k < 8; ++k) {
            trow[k * 36 + colA] = (unsigned)(unsigned short)ra0[k] |
                                  ((unsigned)(unsigned short)ra1[k] << 16);
            trow[k * 36 + colB] = (unsigned)(unsigned short)rb0[k] |
                                  ((unsigned)(unsigned short)rb1[k] << 16);
        }
        __syncthreads();
        if (lc < 7) {
            XC_LOADG(lc + 1);
            XC_LOADA(lc + 1, a0n, a1n);
        }
#pragma unroll
        for (int ks = 0; ks < 2; ++ks) {
            int q = ks * 4 + lg;
#pragma unroll
            for (int dd = 0; dd < 2; ++dd) {
                int dloc = w * 32 + dd * 16 + l15;
                int qs = q ^ ((dloc >> 3) & 7);
                bf16x8 bb = *(const bf16x8*)&tile[dloc * 36 + qs * 4];
                acc[0][dd] = __builtin_amdgcn_mfma_f32_16x16x32_bf16(a0c[ks], bb, acc[0][dd], 0, 0, 0);
                acc[1][dd] = __builtin_amdgcn_mfma_f32_16x16x32_bf16(a1c[ks], bb, acc[1][dd], 0, 0, 0);
            }
        }
        __syncthreads();
        if (lc < 7) {
#pragma unroll
            for (int ks = 0; ks < 2; ++ks) { a0c[ks] = a0n[ks]; a1c[ks] = a1n[ks]; }
        }
    }
#undef XC_LOADG
#undef XC_LOADA
#pragma unroll
    for (int h = 0; h < 2; ++h)
#pragma unroll
        for (int dd = 0; dd < 2; ++dd)
#pragma unroll
            for (int r = 0; r < 4; ++r) {
                int c = 16 * h + lg * 4 + r;
                int d = dt * 128 + w * 32 + dd * 16 + l15;
                x_cb[((size_t)c * Bn + b) * Dn + d] = (short)f2bf(acc[h][dd][r]);
            }
}

// ---------------------------------------------------------------------------
extern "C" void kernel_launch(void* const* d_in, const int* in_sizes, int n_in,
                              void* d_out, int out_size, void* d_ws, size_t ws_size,
                              hipStream_t stream) {
    const float* in   = (const float*)d_in[0];
    const float* fc_w = (const float*)d_in[1];
    const float* fc_b = (const float*)d_in[2];
    float* out = (float*)d_out;

    char* p = (char*)d_ws;
    auto alloc = [&](size_t bytes) -> char* {
        char* r = p;
        p += (bytes + 255) & ~(size_t)255;
        return r;
    };
    short* in_bf  = (short*)alloc((size_t)Bn * Ln * Dn * 2);   // 64 MB
    short* fc_wT  = (short*)alloc((size_t)COn * Dn * 2);       // 4 MB
    short* fc_wb  = (short*)alloc((size_t)COn * Dn * 2);       // 4 MB
    short* w_vb   = (short*)alloc((size_t)Bn * Cn * Dn * 2);   // 4 MB
    short* c_wT   = (short*)alloc((size_t)Bn * Cn * Ln * 2);   // 2 MB
    short* x_cb   = (short*)alloc((size_t)Cn * Bn * Dn * 2);   // 4 MB
    short* v_bf   = (short*)alloc((size_t)Bn * Cn * On * 2);   // 256 KB
    float* rs_p   = (float*)alloc((size_t)Bn * 16 * Dn * 4);   // 4 MB
    unsigned short* rs_bf = (unsigned short*)alloc((size_t)Bn * Dn * 2);
    float* b_ij   = (float*)alloc((size_t)Bn * Ln * Cn * 4);   // 4 MB
    float* bias_v = (float*)alloc((size_t)Bn * Cn * 4);
    float* csum_p = (float*)alloc((size_t)16 * Bn * Cn * 4);

    k_ctr<<<dim3(16, Bn), 256, 0, stream>>>(in, in_bf, rs_p);
    k_prep2<<<384, 256, 0, stream>>>(fc_w, fc_wT, fc_wb, rs_p, rs_bf);
    k_sv3<<<dim3(4, Cn), 64, 0, stream>>>((const short*)rs_bf, csum_p, fc_wT,
                                          fc_b, v_bf, nullptr, bias_v, 1);
    for (int it = 1; it <= 2; ++it) {
        k_wv_m<<<dim3(4, Cn), 256, 0, stream>>>(fc_wb, v_bf, w_vb);
        k_route2<<<dim3(16, Bn), 256, 0, stream>>>(in_bf, w_vb, bias_v, b_ij,
                                                   c_wT, csum_p,
                                                   (it == 1) ? 1 : 0,
                                                   (it == 2) ? 1 : 0);
        k_xc_m<<<dim3(8, Bn), 256, 0, stream>>>(in_bf, c_wT, x_cb);
        k_sv3<<<dim3(4, Cn), 64, 0, stream>>>(x_cb, csum_p, fc_wT, fc_b,
                                              v_bf, (it == 2) ? out : nullptr,
                                              bias_v, 0);
    }
}